// Round 1
// baseline (1961.293 us; speedup 1.0000x reference)
//
#include <hip/hip_runtime.h>
#include <math.h>

#define NG 64
#define NM 256
#define ND 256
#define NK 16
#define NR (NG * NM)  // 16384 rows total

constexpr float LOGM_C = -0.10536051565782628f;  // log(0.9)

// ---------------- GEMM NN: C[M,N] = act(A[M,K] @ B[K,N] + bias) ----------------
// grid: (N/64, M/64), block 256. 64x64 tile, BK=16, 4x4 micro-tile.
template <bool RELU, bool BIAS>
__global__ __launch_bounds__(256) void gemm_nn_k(const float* __restrict__ A,
                                                 const float* __restrict__ B,
                                                 const float* __restrict__ bias,
                                                 float* __restrict__ C, int N, int K) {
  __shared__ float As[16][68];  // [k][row], padded
  __shared__ float Bs[16][64];  // [k][col]
  const int tid = threadIdx.x;
  const int tx = tid & 15, ty = tid >> 4;
  const int m0 = blockIdx.y * 64, n0 = blockIdx.x * 64;
  float acc[4][4] = {};
  const int ar = tid >> 2, akc = (tid & 3) * 4;
  const int bkr = tid >> 4, bc = (tid & 15) * 4;
  for (int k0 = 0; k0 < K; k0 += 16) {
    float4 av = *(const float4*)&A[(size_t)(m0 + ar) * K + k0 + akc];
    As[akc + 0][ar] = av.x;
    As[akc + 1][ar] = av.y;
    As[akc + 2][ar] = av.z;
    As[akc + 3][ar] = av.w;
    *(float4*)&Bs[bkr][bc] = *(const float4*)&B[(size_t)(k0 + bkr) * N + n0 + bc];
    __syncthreads();
#pragma unroll
    for (int kk = 0; kk < 16; ++kk) {
      const float4 a = *(const float4*)&As[kk][ty * 4];
      const float4 b = *(const float4*)&Bs[kk][tx * 4];
      const float aa[4] = {a.x, a.y, a.z, a.w};
      const float bb[4] = {b.x, b.y, b.z, b.w};
#pragma unroll
      for (int i = 0; i < 4; ++i)
#pragma unroll
        for (int j = 0; j < 4; ++j) acc[i][j] = fmaf(aa[i], bb[j], acc[i][j]);
    }
    __syncthreads();
  }
  float4 bv = {0.f, 0.f, 0.f, 0.f};
  if (BIAS) bv = *(const float4*)&bias[n0 + tx * 4];
#pragma unroll
  for (int i = 0; i < 4; ++i) {
    float4 o = {acc[i][0], acc[i][1], acc[i][2], acc[i][3]};
    if (BIAS) {
      o.x += bv.x;
      o.y += bv.y;
      o.z += bv.z;
      o.w += bv.w;
    }
    if (RELU) {
      o.x = fmaxf(o.x, 0.f);
      o.y = fmaxf(o.y, 0.f);
      o.z = fmaxf(o.z, 0.f);
      o.w = fmaxf(o.w, 0.f);
    }
    *(float4*)&C[(size_t)(m0 + ty * 4 + i) * N + n0 + tx * 4] = o;
  }
}

// ---------------- batched GEMM NT per graph: C_g = A_g[256,256] @ B_g[256,256]^T ----
// grid: (4,4,NG), block 256. COST epilogue: C = acc/(nA*nB*lam)
template <bool COST>
__global__ __launch_bounds__(256) void gemm_nt_k(const float* __restrict__ A,
                                                 const float* __restrict__ B,
                                                 float* __restrict__ C,
                                                 const float* __restrict__ nA,
                                                 const float* __restrict__ nB,
                                                 const float* __restrict__ eps) {
  __shared__ float As[16][68];
  __shared__ float Bs[16][68];
  const int g = blockIdx.z;
  const float* Ag = A + (size_t)g * NM * ND;
  const float* Bg = B + (size_t)g * NM * ND;
  const int tid = threadIdx.x;
  const int tx = tid & 15, ty = tid >> 4;
  const int m0 = blockIdx.y * 64, n0 = blockIdx.x * 64;
  float acc[4][4] = {};
  const int r = tid >> 2, kc = (tid & 3) * 4;
  for (int k0 = 0; k0 < ND; k0 += 16) {
    float4 av = *(const float4*)&Ag[(size_t)(m0 + r) * ND + k0 + kc];
    As[kc + 0][r] = av.x;
    As[kc + 1][r] = av.y;
    As[kc + 2][r] = av.z;
    As[kc + 3][r] = av.w;
    float4 bvv = *(const float4*)&Bg[(size_t)(n0 + r) * ND + k0 + kc];
    Bs[kc + 0][r] = bvv.x;
    Bs[kc + 1][r] = bvv.y;
    Bs[kc + 2][r] = bvv.z;
    Bs[kc + 3][r] = bvv.w;
    __syncthreads();
#pragma unroll
    for (int kk = 0; kk < 16; ++kk) {
      const float4 a = *(const float4*)&As[kk][ty * 4];
      const float4 b = *(const float4*)&Bs[kk][tx * 4];
      const float aa[4] = {a.x, a.y, a.z, a.w};
      const float bb[4] = {b.x, b.y, b.z, b.w};
#pragma unroll
      for (int i = 0; i < 4; ++i)
#pragma unroll
        for (int j = 0; j < 4; ++j) acc[i][j] = fmaf(aa[i], bb[j], acc[i][j]);
    }
    __syncthreads();
  }
  if (COST) {
    const float inv_lam = 1.0f / (expf(eps[0]) + 0.03f);
    const float nb0 = nB[g * NM + n0 + tx * 4 + 0];
    const float nb1 = nB[g * NM + n0 + tx * 4 + 1];
    const float nb2 = nB[g * NM + n0 + tx * 4 + 2];
    const float nb3 = nB[g * NM + n0 + tx * 4 + 3];
#pragma unroll
    for (int i = 0; i < 4; ++i) {
      const int m = m0 + ty * 4 + i;
      const float sc = inv_lam / nA[g * NM + m];
      float4 o = {acc[i][0] * sc / nb0, acc[i][1] * sc / nb1, acc[i][2] * sc / nb2,
                  acc[i][3] * sc / nb3};
      *(float4*)&C[(size_t)g * NM * NM + (size_t)m * NM + n0 + tx * 4] = o;
    }
  } else {
#pragma unroll
    for (int i = 0; i < 4; ++i) {
      const int m = m0 + ty * 4 + i;
      float4 o = {acc[i][0], acc[i][1], acc[i][2], acc[i][3]};
      *(float4*)&C[(size_t)g * NM * NM + (size_t)m * NM + n0 + tx * 4] = o;
    }
  }
}

// ---------------- per-row sum of squares ----------------
__global__ __launch_bounds__(256) void rowsq_k(const float* __restrict__ h,
                                               float* __restrict__ sq) {
  const int w = threadIdx.x >> 6, lane = threadIdx.x & 63;
  const int row = blockIdx.x * 4 + w;
  float4 v = *(const float4*)&h[(size_t)row * ND + lane * 4];
  float s = v.x * v.x + v.y * v.y + v.z * v.z + v.w * v.w;
#pragma unroll
  for (int off = 32; off; off >>= 1) s += __shfl_xor(s, off);
  if (lane == 0) sq[row] = s;
}

// ---------------- top-16 nearest neighbors (wave per row) ----------------
__global__ __launch_bounds__(256) void topk_k(const float* __restrict__ S,
                                              const float* __restrict__ sq,
                                              int* __restrict__ idx) {
  const int w = threadIdx.x >> 6, lane = threadIdx.x & 63;
  const int row = blockIdx.x * 4 + w;
  const int g = row >> 8, m = row & 255;
  const float* Srow = S + (size_t)row * NM;
  const float* sqg = sq + g * NM;
  const float sm = sqg[m];
  const float4 sv = *(const float4*)&Srow[lane * 4];
  const float4 qv = *(const float4*)&sqg[lane * 4];
  float cand[4] = {sm + qv.x - 2.f * sv.x, sm + qv.y - 2.f * sv.y, sm + qv.z - 2.f * sv.z,
                   sm + qv.w - 2.f * sv.w};
#pragma unroll
  for (int t = 0; t < 4; ++t)
    if (lane * 4 + t == m) cand[t] = 1e30f;
  for (int rnd = 0; rnd < NK; ++rnd) {
    float bvv = cand[0];
    int bi = lane * 4;
#pragma unroll
    for (int t = 1; t < 4; ++t)
      if (cand[t] < bvv) {
        bvv = cand[t];
        bi = lane * 4 + t;
      }
#pragma unroll
    for (int off = 1; off < 64; off <<= 1) {
      const float ov = __shfl_xor(bvv, off);
      const int oi = __shfl_xor(bi, off);
      if (ov < bvv || (ov == bvv && oi < bi)) {
        bvv = ov;
        bi = oi;
      }
    }
    if (lane == 0) idx[(size_t)row * NK + rnd] = bi;
    if ((bi >> 2) == lane) cand[bi & 3] = 1e30f;
  }
}

// ---------------- edge MLP + max aggregation + feature norm ----------------
// block per node (g,m); 256 threads (one per output channel)
__global__ __launch_bounds__(256) void edgemlp_k(
    const float* __restrict__ c1, const float* __restrict__ n1, const int* __restrict__ idx,
    const float* __restrict__ b1, const float* __restrict__ W2, const float* __restrict__ b2,
    float* __restrict__ feat, float* __restrict__ nrm) {
  __shared__ float Rs[NK][ND];
  __shared__ int sidx[NK];
  __shared__ float red[4];
  const int rrow = blockIdx.x;  // g*256+m
  const int g = rrow >> 8;
  const int tid = threadIdx.x;
  if (tid < NK) sidx[tid] = idx[(size_t)rrow * NK + tid];
  __syncthreads();
  const float base = c1[(size_t)rrow * ND + tid] - n1[(size_t)rrow * ND + tid] + b1[tid];
#pragma unroll
  for (int j = 0; j < NK; ++j) {
    const float nj = n1[(size_t)(g * NM + sidx[j]) * ND + tid];
    Rs[j][tid] = fmaxf(base + nj, 0.f);
  }
  __syncthreads();
  float acc[NK];
#pragma unroll
  for (int j = 0; j < NK; ++j) acc[j] = 0.f;
  for (int d0 = 0; d0 < ND; d0 += 4) {
    const float w0 = W2[(size_t)(d0 + 0) * ND + tid];
    const float w1 = W2[(size_t)(d0 + 1) * ND + tid];
    const float w2v = W2[(size_t)(d0 + 2) * ND + tid];
    const float w3 = W2[(size_t)(d0 + 3) * ND + tid];
#pragma unroll
    for (int j = 0; j < NK; ++j) {
      const float4 rv = *(const float4*)&Rs[j][d0];
      acc[j] = fmaf(rv.x, w0, fmaf(rv.y, w1, fmaf(rv.z, w2v, fmaf(rv.w, w3, acc[j]))));
    }
  }
  float vmax = acc[0];
#pragma unroll
  for (int j = 1; j < NK; ++j) vmax = fmaxf(vmax, acc[j]);
  const float out = vmax + b2[tid];
  feat[(size_t)rrow * ND + tid] = out;
  float s = out * out;
#pragma unroll
  for (int off = 32; off; off >>= 1) s += __shfl_xor(s, off);
  if ((tid & 63) == 0) red[tid >> 6] = s;
  __syncthreads();
  if (tid == 0) nrm[rrow] = sqrtf(red[0] + red[1] + red[2] + red[3]);
}

// ---------------- Sinkhorn row normalize (axis=2), wave per row ----------------
template <bool FINAL>
__global__ __launch_bounds__(256) void sink_row_k(float* __restrict__ P) {
  const int w = threadIdx.x >> 6, lane = threadIdx.x & 63;
  const size_t row = (size_t)blockIdx.x * 4 + w;
  float* p = P + row * NM;
  float4 v = *(const float4*)&p[lane * 4];
  float mx = fmaxf(fmaxf(v.x, v.y), fmaxf(v.z, v.w));
#pragma unroll
  for (int off = 32; off; off >>= 1) mx = fmaxf(mx, __shfl_xor(mx, off));
  float s = expf(v.x - mx) + expf(v.y - mx) + expf(v.z - mx) + expf(v.w - mx);
#pragma unroll
  for (int off = 32; off; off >>= 1) s += __shfl_xor(s, off);
  const float delta = mx + logf(s) - LOGM_C;
  v.x -= delta;
  v.y -= delta;
  v.z -= delta;
  v.w -= delta;
  if (FINAL) {
    v.x = expf(v.x);
    v.y = expf(v.y);
    v.z = expf(v.z);
    v.w = expf(v.w);
  }
  *(float4*)&p[lane * 4] = v;
}

// ---------------- Sinkhorn column normalize (axis=1) ----------------
// grid (NG, 4), block 64: thread owns one column, online LSE then subtract.
__global__ __launch_bounds__(64) void sink_col_k(float* __restrict__ P) {
  const int g = blockIdx.x;
  const int col = blockIdx.y * 64 + threadIdx.x;
  float* Pg = P + (size_t)g * NM * NM;
  float mx = -INFINITY, s = 0.f;
  for (int r2 = 0; r2 < NM; ++r2) {
    const float x = Pg[(size_t)r2 * NM + col];
    const float m2 = fmaxf(mx, x);
    s = s * expf(mx - m2) + expf(x - m2);
    mx = m2;
  }
  const float delta = mx + logf(s) - LOGM_C;
  for (int r2 = 0; r2 < NM; ++r2) Pg[(size_t)r2 * NM + col] -= delta;
}

extern "C" void kernel_launch(void* const* d_in, const int* in_sizes, int n_in, void* d_out,
                              int out_size, void* d_ws, size_t ws_size, hipStream_t stream) {
  const float* tra_x = (const float*)d_in[0];
  const float* det_x = (const float*)d_in[1];
  const float* W_enc = (const float*)d_in[2];
  const float* b_enc = (const float*)d_in[3];
  const float* W1 = (const float*)d_in[4];
  const float* b1 = (const float*)d_in[5];
  const float* W2 = (const float*)d_in[6];
  const float* b2 = (const float*)d_in[7];
  const float* eps = (const float*)d_in[8];
  float* out = (float*)d_out;

  float* ws = (float*)d_ws;
  const size_t SZ = (size_t)NR * ND;
  float* h = ws;
  float* c1 = h + SZ;
  float* n1 = c1 + SZ;
  float* featT = n1 + SZ;
  float* featD = featT + SZ;
  float* sq = featD + SZ;
  float* nT = sq + NR;
  float* nD = nT + NR;
  int* idx = (int*)(nD + NR);
  float* S = out;  // gram scratch lives in d_out until the cost kernel overwrites it

  const float* xs[2] = {tra_x, det_x};
  float* feats[2] = {featT, featD};
  float* nrms[2] = {nT, nD};

  for (int s2 = 0; s2 < 2; ++s2) {
    gemm_nn_k<true, true><<<dim3(4, 256), 256, 0, stream>>>(xs[s2], W_enc, b_enc, h, 256, 256);
    gemm_nn_k<false, false><<<dim3(4, 256), 256, 0, stream>>>(h, W1, nullptr, c1, 256, 256);
    gemm_nn_k<false, false>
        <<<dim3(4, 256), 256, 0, stream>>>(h, W1 + 256 * 256, nullptr, n1, 256, 256);
    rowsq_k<<<4096, 256, 0, stream>>>(h, sq);
    gemm_nt_k<false><<<dim3(4, 4, NG), 256, 0, stream>>>(h, h, S, nullptr, nullptr, nullptr);
    topk_k<<<4096, 256, 0, stream>>>(S, sq, idx);
    edgemlp_k<<<16384, 256, 0, stream>>>(c1, n1, idx, b1, W2, b2, feats[s2], nrms[s2]);
  }
  gemm_nt_k<true><<<dim3(4, 4, NG), 256, 0, stream>>>(featT, featD, out, nT, nD, eps);
  for (int it = 0; it < 7; ++it) {
    sink_row_k<false><<<4096, 256, 0, stream>>>(out);
    sink_col_k<<<dim3(NG, 4), 64, 0, stream>>>(out);
  }
  sink_row_k<true><<<4096, 256, 0, stream>>>(out);
}

// Round 2
// 1306.017 us; speedup vs baseline: 1.5017x; 1.5017x over previous
//
#include <hip/hip_runtime.h>
#include <math.h>

#define NG 64
#define NM 256
#define ND 256
#define NK 16
#define NR (NG * NM)  // 16384 rows total

constexpr float LOGM_C = -0.10536051565782628f;  // log(0.9)

typedef __attribute__((ext_vector_type(8))) short bf16x8;
typedef __attribute__((ext_vector_type(4))) float f32x4;

static __device__ __forceinline__ short f2bf(float x) {
  union {
    float f;
    unsigned u;
  } v;
  v.f = x;
  unsigned r = v.u + 0x7FFFu + ((v.u >> 16) & 1u);
  return (short)(r >> 16);
}

// ---------------- GEMM NN: C[M,N] = act(A[M,K] @ B[K,N] + bias - sub) -------
// grid: (N/64, M/64), block 256. 64x64 tile, BK=16, 4x4 micro-tile.
template <bool RELU, bool BIAS, bool SUB>
__global__ __launch_bounds__(256) void gemm_nn_k(const float* __restrict__ A,
                                                 const float* __restrict__ B,
                                                 const float* __restrict__ bias,
                                                 const float* __restrict__ sub,
                                                 float* __restrict__ C, int N, int K) {
  __shared__ float As[16][68];  // [k][row], padded
  __shared__ float Bs[16][64];  // [k][col]
  const int tid = threadIdx.x;
  const int tx = tid & 15, ty = tid >> 4;
  const int m0 = blockIdx.y * 64, n0 = blockIdx.x * 64;
  float acc[4][4] = {};
  const int ar = tid >> 2, akc = (tid & 3) * 4;
  const int bkr = tid >> 4, bc = (tid & 15) * 4;
  for (int k0 = 0; k0 < K; k0 += 16) {
    float4 av = *(const float4*)&A[(size_t)(m0 + ar) * K + k0 + akc];
    As[akc + 0][ar] = av.x;
    As[akc + 1][ar] = av.y;
    As[akc + 2][ar] = av.z;
    As[akc + 3][ar] = av.w;
    *(float4*)&Bs[bkr][bc] = *(const float4*)&B[(size_t)(k0 + bkr) * N + n0 + bc];
    __syncthreads();
#pragma unroll
    for (int kk = 0; kk < 16; ++kk) {
      const float4 a = *(const float4*)&As[kk][ty * 4];
      const float4 b = *(const float4*)&Bs[kk][tx * 4];
      const float aa[4] = {a.x, a.y, a.z, a.w};
      const float bb[4] = {b.x, b.y, b.z, b.w};
#pragma unroll
      for (int i = 0; i < 4; ++i)
#pragma unroll
        for (int j = 0; j < 4; ++j) acc[i][j] = fmaf(aa[i], bb[j], acc[i][j]);
    }
    __syncthreads();
  }
  float4 bv = {0.f, 0.f, 0.f, 0.f};
  if (BIAS) bv = *(const float4*)&bias[n0 + tx * 4];
#pragma unroll
  for (int i = 0; i < 4; ++i) {
    float4 o = {acc[i][0], acc[i][1], acc[i][2], acc[i][3]};
    if (BIAS) {
      o.x += bv.x;
      o.y += bv.y;
      o.z += bv.z;
      o.w += bv.w;
    }
    if (SUB) {
      float4 sv = *(const float4*)&sub[(size_t)(m0 + ty * 4 + i) * N + n0 + tx * 4];
      o.x -= sv.x;
      o.y -= sv.y;
      o.z -= sv.z;
      o.w -= sv.w;
    }
    if (RELU) {
      o.x = fmaxf(o.x, 0.f);
      o.y = fmaxf(o.y, 0.f);
      o.z = fmaxf(o.z, 0.f);
      o.w = fmaxf(o.w, 0.f);
    }
    *(float4*)&C[(size_t)(m0 + ty * 4 + i) * N + n0 + tx * 4] = o;
  }
}

// ---------------- batched GEMM NT per graph: C_g = A_g[256,256] @ B_g[256,256]^T ----
template <bool COST>
__global__ __launch_bounds__(256) void gemm_nt_k(const float* __restrict__ A,
                                                 const float* __restrict__ B,
                                                 float* __restrict__ C,
                                                 const float* __restrict__ nA,
                                                 const float* __restrict__ nB,
                                                 const float* __restrict__ eps) {
  __shared__ float As[16][68];
  __shared__ float Bs[16][68];
  const int g = blockIdx.z;
  const float* Ag = A + (size_t)g * NM * ND;
  const float* Bg = B + (size_t)g * NM * ND;
  const int tid = threadIdx.x;
  const int tx = tid & 15, ty = tid >> 4;
  const int m0 = blockIdx.y * 64, n0 = blockIdx.x * 64;
  float acc[4][4] = {};
  const int r = tid >> 2, kc = (tid & 3) * 4;
  for (int k0 = 0; k0 < ND; k0 += 16) {
    float4 av = *(const float4*)&Ag[(size_t)(m0 + r) * ND + k0 + kc];
    As[kc + 0][r] = av.x;
    As[kc + 1][r] = av.y;
    As[kc + 2][r] = av.z;
    As[kc + 3][r] = av.w;
    float4 bvv = *(const float4*)&Bg[(size_t)(n0 + r) * ND + k0 + kc];
    Bs[kc + 0][r] = bvv.x;
    Bs[kc + 1][r] = bvv.y;
    Bs[kc + 2][r] = bvv.z;
    Bs[kc + 3][r] = bvv.w;
    __syncthreads();
#pragma unroll
    for (int kk = 0; kk < 16; ++kk) {
      const float4 a = *(const float4*)&As[kk][ty * 4];
      const float4 b = *(const float4*)&Bs[kk][tx * 4];
      const float aa[4] = {a.x, a.y, a.z, a.w};
      const float bb[4] = {b.x, b.y, b.z, b.w};
#pragma unroll
      for (int i = 0; i < 4; ++i)
#pragma unroll
        for (int j = 0; j < 4; ++j) acc[i][j] = fmaf(aa[i], bb[j], acc[i][j]);
    }
    __syncthreads();
  }
  if (COST) {
    const float inv_lam = 1.0f / (expf(eps[0]) + 0.03f);
    const float nb0 = nB[g * NM + n0 + tx * 4 + 0];
    const float nb1 = nB[g * NM + n0 + tx * 4 + 1];
    const float nb2 = nB[g * NM + n0 + tx * 4 + 2];
    const float nb3 = nB[g * NM + n0 + tx * 4 + 3];
#pragma unroll
    for (int i = 0; i < 4; ++i) {
      const int m = m0 + ty * 4 + i;
      const float sc = inv_lam / nA[g * NM + m];
      float4 o = {acc[i][0] * sc / nb0, acc[i][1] * sc / nb1, acc[i][2] * sc / nb2,
                  acc[i][3] * sc / nb3};
      *(float4*)&C[(size_t)g * NM * NM + (size_t)m * NM + n0 + tx * 4] = o;
    }
  } else {
#pragma unroll
    for (int i = 0; i < 4; ++i) {
      const int m = m0 + ty * 4 + i;
      float4 o = {acc[i][0], acc[i][1], acc[i][2], acc[i][3]};
      *(float4*)&C[(size_t)g * NM * NM + (size_t)m * NM + n0 + tx * 4] = o;
    }
  }
}

// ---------------- per-row sum of squares ----------------
__global__ __launch_bounds__(256) void rowsq_k(const float* __restrict__ h,
                                               float* __restrict__ sq) {
  const int w = threadIdx.x >> 6, lane = threadIdx.x & 63;
  const int row = blockIdx.x * 4 + w;
  float4 v = *(const float4*)&h[(size_t)row * ND + lane * 4];
  float s = v.x * v.x + v.y * v.y + v.z * v.z + v.w * v.w;
#pragma unroll
  for (int off = 32; off; off >>= 1) s += __shfl_xor(s, off);
  if (lane == 0) sq[row] = s;
}

// ---------------- top-16 nearest neighbors (wave per row) ----------------
__global__ __launch_bounds__(256) void topk_k(const float* __restrict__ S,
                                              const float* __restrict__ sq,
                                              int* __restrict__ idx) {
  const int w = threadIdx.x >> 6, lane = threadIdx.x & 63;
  const int row = blockIdx.x * 4 + w;
  const int g = row >> 8, m = row & 255;
  const float* Srow = S + (size_t)row * NM;
  const float* sqg = sq + g * NM;
  const float sm = sqg[m];
  const float4 sv = *(const float4*)&Srow[lane * 4];
  const float4 qv = *(const float4*)&sqg[lane * 4];
  float cand[4] = {sm + qv.x - 2.f * sv.x, sm + qv.y - 2.f * sv.y, sm + qv.z - 2.f * sv.z,
                   sm + qv.w - 2.f * sv.w};
#pragma unroll
  for (int t = 0; t < 4; ++t)
    if (lane * 4 + t == m) cand[t] = 1e30f;
  for (int rnd = 0; rnd < NK; ++rnd) {
    float bvv = cand[0];
    int bi = lane * 4;
#pragma unroll
    for (int t = 1; t < 4; ++t)
      if (cand[t] < bvv) {
        bvv = cand[t];
        bi = lane * 4 + t;
      }
#pragma unroll
    for (int off = 1; off < 64; off <<= 1) {
      const float ov = __shfl_xor(bvv, off);
      const int oi = __shfl_xor(bi, off);
      if (ov < bvv || (ov == bvv && oi < bi)) {
        bvv = ov;
        bi = oi;
      }
    }
    if (lane == 0) idx[(size_t)row * NK + rnd] = bi;
    if ((bi >> 2) == lane) cand[bi & 3] = 1e30f;
  }
}

// ---------------- W2 -> bf16 transposed [N=256 cols][K=256] ----------------
__global__ __launch_bounds__(256) void w2t_k(const float* __restrict__ W2,
                                             short* __restrict__ w2t) {
  const int c = blockIdx.x, k = threadIdx.x;
  w2t[c * 256 + k] = f2bf(W2[(size_t)k * 256 + c]);
}

// ---------------- edge MLP via MFMA: wave per node, no LDS ----------------
// R[16 nbrs, 256] = relu(base[m] + n1[idx]); D = R @ W2; feat = max_rows(D)+b2
__global__ __launch_bounds__(256) void edgemlp_mfma_k(
    const float* __restrict__ base, const float* __restrict__ n1, const int* __restrict__ idx,
    const short* __restrict__ w2t, const float* __restrict__ b2, float* __restrict__ feat,
    float* __restrict__ nrm) {
  const int wv = threadIdx.x >> 6, l = threadIdx.x & 63;
  const int node = blockIdx.x * 4 + wv;
  const int g = node >> 8;
  const int r = l & 15, gq = l >> 4;  // r = neighbor row, gq = k-group
  const int nbr = idx[(size_t)node * NK + r];
  const float* bs = base + (size_t)node * ND;
  const float* ns = n1 + (size_t)(g * NM + nbr) * ND;
  // Build A-fragments (R rows) in registers: afr[ks][j] = R[r][ks*32 + gq*8 + j]
  bf16x8 afr[8];
#pragma unroll
  for (int ks = 0; ks < 8; ++ks) {
    const int k0 = ks * 32 + gq * 8;
    const float4 b0 = *(const float4*)&bs[k0];
    const float4 b1v = *(const float4*)&bs[k0 + 4];
    const float4 n0 = *(const float4*)&ns[k0];
    const float4 n1v = *(const float4*)&ns[k0 + 4];
    float e[8] = {b0.x + n0.x, b0.y + n0.y, b0.z + n0.z, b0.w + n0.w,
                  b1v.x + n1v.x, b1v.y + n1v.y, b1v.z + n1v.z, b1v.w + n1v.w};
#pragma unroll
    for (int j = 0; j < 8; ++j) afr[ks][j] = f2bf(fmaxf(e[j], 0.f));
  }
  f32x4 acc[16];
#pragma unroll
  for (int nb = 0; nb < 16; ++nb) acc[nb] = (f32x4){0.f, 0.f, 0.f, 0.f};
  const short* wbase = w2t + (size_t)r * 256 + gq * 8;  // col = nb*16 + r, k base
#pragma unroll
  for (int ks = 0; ks < 8; ++ks) {
    const short* wk = wbase + ks * 32;
#pragma unroll
    for (int nb = 0; nb < 16; ++nb) {
      const bf16x8 bfr = *(const bf16x8*)(wk + (size_t)nb * 16 * 256);
      acc[nb] = __builtin_amdgcn_mfma_f32_16x16x32_bf16(afr[ks], bfr, acc[nb], 0, 0, 0);
    }
  }
  // epilogue: max over 16 rows (4 regs x 4 lane-groups), add b2, norm
  float s = 0.f;
  float outs[16];
#pragma unroll
  for (int nb = 0; nb < 16; ++nb) {
    float m1 = fmaxf(fmaxf(acc[nb][0], acc[nb][1]), fmaxf(acc[nb][2], acc[nb][3]));
    m1 = fmaxf(m1, __shfl_xor(m1, 16));
    m1 = fmaxf(m1, __shfl_xor(m1, 32));
    const float o = m1 + b2[nb * 16 + r];
    outs[nb] = o;
    s += o * o;
  }
  if (gq == 0) {
#pragma unroll
    for (int nb = 0; nb < 16; ++nb) feat[(size_t)node * ND + nb * 16 + r] = outs[nb];
  }
#pragma unroll
  for (int off = 1; off < 16; off <<= 1) s += __shfl_xor(s, off);
  if (l == 0) nrm[node] = sqrtf(s);
}

// ---------------- Sinkhorn row normalize (axis=2), wave per row ----------------
template <bool FINAL>
__global__ __launch_bounds__(256) void sink_row_k(float* __restrict__ P) {
  const int w = threadIdx.x >> 6, lane = threadIdx.x & 63;
  const size_t row = (size_t)blockIdx.x * 4 + w;
  float* p = P + row * NM;
  float4 v = *(const float4*)&p[lane * 4];
  float mx = fmaxf(fmaxf(v.x, v.y), fmaxf(v.z, v.w));
#pragma unroll
  for (int off = 32; off; off >>= 1) mx = fmaxf(mx, __shfl_xor(mx, off));
  float s = expf(v.x - mx) + expf(v.y - mx) + expf(v.z - mx) + expf(v.w - mx);
#pragma unroll
  for (int off = 32; off; off >>= 1) s += __shfl_xor(s, off);
  const float delta = mx + logf(s) - LOGM_C;
  v.x -= delta;
  v.y -= delta;
  v.z -= delta;
  v.w -= delta;
  if (FINAL) {
    v.x = expf(v.x);
    v.y = expf(v.y);
    v.z = expf(v.z);
    v.w = expf(v.w);
  }
  *(float4*)&p[lane * 4] = v;
}

// ---------------- Sinkhorn column normalize (axis=1) ----------------
__global__ __launch_bounds__(64) void sink_col_k(float* __restrict__ P) {
  const int g = blockIdx.x;
  const int col = blockIdx.y * 64 + threadIdx.x;
  float* Pg = P + (size_t)g * NM * NM;
  float mx = -INFINITY, s = 0.f;
  for (int r2 = 0; r2 < NM; ++r2) {
    const float x = Pg[(size_t)r2 * NM + col];
    const float m2 = fmaxf(mx, x);
    s = s * expf(mx - m2) + expf(x - m2);
    mx = m2;
  }
  const float delta = mx + logf(s) - LOGM_C;
  for (int r2 = 0; r2 < NM; ++r2) Pg[(size_t)r2 * NM + col] -= delta;
}

extern "C" void kernel_launch(void* const* d_in, const int* in_sizes, int n_in, void* d_out,
                              int out_size, void* d_ws, size_t ws_size, hipStream_t stream) {
  const float* tra_x = (const float*)d_in[0];
  const float* det_x = (const float*)d_in[1];
  const float* W_enc = (const float*)d_in[2];
  const float* b_enc = (const float*)d_in[3];
  const float* W1 = (const float*)d_in[4];
  const float* b1 = (const float*)d_in[5];
  const float* W2 = (const float*)d_in[6];
  const float* b2 = (const float*)d_in[7];
  const float* eps = (const float*)d_in[8];
  float* out = (float*)d_out;

  float* ws = (float*)d_ws;
  const size_t SZ = (size_t)NR * ND;
  float* h = ws;
  float* n1b = h + SZ;
  float* baseb = n1b + SZ;
  float* featT = baseb + SZ;
  float* featD = featT + SZ;
  float* sq = featD + SZ;
  float* nT = sq + NR;
  float* nD = nT + NR;
  int* idx = (int*)(nD + NR);
  short* w2t = (short*)(idx + (size_t)NR * NK);
  float* S = out;  // gram scratch lives in d_out until the cost kernel overwrites it

  const float* xs[2] = {tra_x, det_x};
  float* feats[2] = {featT, featD};
  float* nrms[2] = {nT, nD};

  w2t_k<<<256, 256, 0, stream>>>(W2, w2t);
  for (int s2 = 0; s2 < 2; ++s2) {
    gemm_nn_k<true, true, false>
        <<<dim3(4, 256), 256, 0, stream>>>(xs[s2], W_enc, b_enc, nullptr, h, 256, 256);
    gemm_nn_k<false, false, false>
        <<<dim3(4, 256), 256, 0, stream>>>(h, W1 + 256 * 256, nullptr, nullptr, n1b, 256, 256);
    gemm_nn_k<false, true, true>
        <<<dim3(4, 256), 256, 0, stream>>>(h, W1, b1, n1b, baseb, 256, 256);
    rowsq_k<<<4096, 256, 0, stream>>>(h, sq);
    gemm_nt_k<false><<<dim3(4, 4, NG), 256, 0, stream>>>(h, h, S, nullptr, nullptr, nullptr);
    topk_k<<<4096, 256, 0, stream>>>(S, sq, idx);
    edgemlp_mfma_k<<<4096, 256, 0, stream>>>(baseb, n1b, idx, w2t, b2, feats[s2], nrms[s2]);
  }
  gemm_nt_k<true><<<dim3(4, 4, NG), 256, 0, stream>>>(featT, featD, out, nT, nD, eps);
  for (int it = 0; it < 7; ++it) {
    sink_row_k<false><<<4096, 256, 0, stream>>>(out);
    sink_col_k<<<dim3(NG, 4), 64, 0, stream>>>(out);
  }
  sink_row_k<true><<<4096, 256, 0, stream>>>(out);
}

// Round 3
// 916.002 us; speedup vs baseline: 2.1411x; 1.4258x over previous
//
#include <hip/hip_runtime.h>
#include <math.h>

#define NG 64
#define NM 256
#define ND 256
#define NK 16
#define NR (NG * NM)  // 16384 rows total
#define NB 32         // nodes per edge-MLP block

constexpr float LOGM_C = -0.10536051565782628f;  // log(0.9)

typedef __attribute__((ext_vector_type(8))) short bf16x8;
typedef __attribute__((ext_vector_type(4))) float f32x4;

static __device__ __forceinline__ short f2bf(float x) {
  union {
    float f;
    unsigned u;
  } v;
  v.f = x;
  unsigned r = v.u + 0x7FFFu + ((v.u >> 16) & 1u);
  return (short)(r >> 16);
}

// ---------------- GEMM NN: C[M,N] = act(A[M,K] @ B[K,N] + bias - sub) -------
template <bool RELU, bool BIAS, bool SUB>
__global__ __launch_bounds__(256) void gemm_nn_k(const float* __restrict__ A,
                                                 const float* __restrict__ B,
                                                 const float* __restrict__ bias,
                                                 const float* __restrict__ sub,
                                                 float* __restrict__ C, int N, int K) {
  __shared__ float As[16][68];  // [k][row], padded
  __shared__ float Bs[16][64];  // [k][col]
  const int tid = threadIdx.x;
  const int tx = tid & 15, ty = tid >> 4;
  const int m0 = blockIdx.y * 64, n0 = blockIdx.x * 64;
  float acc[4][4] = {};
  const int ar = tid >> 2, akc = (tid & 3) * 4;
  const int bkr = tid >> 4, bc = (tid & 15) * 4;
  for (int k0 = 0; k0 < K; k0 += 16) {
    float4 av = *(const float4*)&A[(size_t)(m0 + ar) * K + k0 + akc];
    As[akc + 0][ar] = av.x;
    As[akc + 1][ar] = av.y;
    As[akc + 2][ar] = av.z;
    As[akc + 3][ar] = av.w;
    *(float4*)&Bs[bkr][bc] = *(const float4*)&B[(size_t)(k0 + bkr) * N + n0 + bc];
    __syncthreads();
#pragma unroll
    for (int kk = 0; kk < 16; ++kk) {
      const float4 a = *(const float4*)&As[kk][ty * 4];
      const float4 b = *(const float4*)&Bs[kk][tx * 4];
      const float aa[4] = {a.x, a.y, a.z, a.w};
      const float bb[4] = {b.x, b.y, b.z, b.w};
#pragma unroll
      for (int i = 0; i < 4; ++i)
#pragma unroll
        for (int j = 0; j < 4; ++j) acc[i][j] = fmaf(aa[i], bb[j], acc[i][j]);
    }
    __syncthreads();
  }
  float4 bv = {0.f, 0.f, 0.f, 0.f};
  if (BIAS) bv = *(const float4*)&bias[n0 + tx * 4];
#pragma unroll
  for (int i = 0; i < 4; ++i) {
    float4 o = {acc[i][0], acc[i][1], acc[i][2], acc[i][3]};
    if (BIAS) {
      o.x += bv.x;
      o.y += bv.y;
      o.z += bv.z;
      o.w += bv.w;
    }
    if (SUB) {
      float4 sv = *(const float4*)&sub[(size_t)(m0 + ty * 4 + i) * N + n0 + tx * 4];
      o.x -= sv.x;
      o.y -= sv.y;
      o.z -= sv.z;
      o.w -= sv.w;
    }
    if (RELU) {
      o.x = fmaxf(o.x, 0.f);
      o.y = fmaxf(o.y, 0.f);
      o.z = fmaxf(o.z, 0.f);
      o.w = fmaxf(o.w, 0.f);
    }
    *(float4*)&C[(size_t)(m0 + ty * 4 + i) * N + n0 + tx * 4] = o;
  }
}

// ---------------- batched GEMM NT per graph: C_g = A_g @ B_g^T ----------------
template <bool COST>
__global__ __launch_bounds__(256) void gemm_nt_k(const float* __restrict__ A,
                                                 const float* __restrict__ B,
                                                 float* __restrict__ C,
                                                 const float* __restrict__ nA,
                                                 const float* __restrict__ nB,
                                                 const float* __restrict__ eps) {
  __shared__ float As[16][68];
  __shared__ float Bs[16][68];
  const int g = blockIdx.z;
  const float* Ag = A + (size_t)g * NM * ND;
  const float* Bg = B + (size_t)g * NM * ND;
  const int tid = threadIdx.x;
  const int tx = tid & 15, ty = tid >> 4;
  const int m0 = blockIdx.y * 64, n0 = blockIdx.x * 64;
  float acc[4][4] = {};
  const int r = tid >> 2, kc = (tid & 3) * 4;
  for (int k0 = 0; k0 < ND; k0 += 16) {
    float4 av = *(const float4*)&Ag[(size_t)(m0 + r) * ND + k0 + kc];
    As[kc + 0][r] = av.x;
    As[kc + 1][r] = av.y;
    As[kc + 2][r] = av.z;
    As[kc + 3][r] = av.w;
    float4 bvv = *(const float4*)&Bg[(size_t)(n0 + r) * ND + k0 + kc];
    Bs[kc + 0][r] = bvv.x;
    Bs[kc + 1][r] = bvv.y;
    Bs[kc + 2][r] = bvv.z;
    Bs[kc + 3][r] = bvv.w;
    __syncthreads();
#pragma unroll
    for (int kk = 0; kk < 16; ++kk) {
      const float4 a = *(const float4*)&As[kk][ty * 4];
      const float4 b = *(const float4*)&Bs[kk][tx * 4];
      const float aa[4] = {a.x, a.y, a.z, a.w};
      const float bb[4] = {b.x, b.y, b.z, b.w};
#pragma unroll
      for (int i = 0; i < 4; ++i)
#pragma unroll
        for (int j = 0; j < 4; ++j) acc[i][j] = fmaf(aa[i], bb[j], acc[i][j]);
    }
    __syncthreads();
  }
  if (COST) {
    const float inv_lam = 1.0f / (expf(eps[0]) + 0.03f);
    const float nb0 = nB[g * NM + n0 + tx * 4 + 0];
    const float nb1 = nB[g * NM + n0 + tx * 4 + 1];
    const float nb2 = nB[g * NM + n0 + tx * 4 + 2];
    const float nb3 = nB[g * NM + n0 + tx * 4 + 3];
#pragma unroll
    for (int i = 0; i < 4; ++i) {
      const int m = m0 + ty * 4 + i;
      const float sc = inv_lam / nA[g * NM + m];
      float4 o = {acc[i][0] * sc / nb0, acc[i][1] * sc / nb1, acc[i][2] * sc / nb2,
                  acc[i][3] * sc / nb3};
      *(float4*)&C[(size_t)g * NM * NM + (size_t)m * NM + n0 + tx * 4] = o;
    }
  } else {
#pragma unroll
    for (int i = 0; i < 4; ++i) {
      const int m = m0 + ty * 4 + i;
      float4 o = {acc[i][0], acc[i][1], acc[i][2], acc[i][3]};
      *(float4*)&C[(size_t)g * NM * NM + (size_t)m * NM + n0 + tx * 4] = o;
    }
  }
}

// ---------------- per-row sum of squares ----------------
__global__ __launch_bounds__(256) void rowsq_k(const float* __restrict__ h,
                                               float* __restrict__ sq) {
  const int w = threadIdx.x >> 6, lane = threadIdx.x & 63;
  const int row = blockIdx.x * 4 + w;
  float4 v = *(const float4*)&h[(size_t)row * ND + lane * 4];
  float s = v.x * v.x + v.y * v.y + v.z * v.z + v.w * v.w;
#pragma unroll
  for (int off = 32; off; off >>= 1) s += __shfl_xor(s, off);
  if (lane == 0) sq[row] = s;
}

// ---------------- per-row L2 norm ----------------
__global__ __launch_bounds__(256) void normrow_k(const float* __restrict__ feat,
                                                 float* __restrict__ nrm) {
  const int w = threadIdx.x >> 6, lane = threadIdx.x & 63;
  const int row = blockIdx.x * 4 + w;
  float4 v = *(const float4*)&feat[(size_t)row * ND + lane * 4];
  float s = v.x * v.x + v.y * v.y + v.z * v.z + v.w * v.w;
#pragma unroll
  for (int off = 32; off; off >>= 1) s += __shfl_xor(s, off);
  if (lane == 0) nrm[row] = sqrtf(s);
}

// ---------------- top-16 nearest neighbors (wave per row) ----------------
__global__ __launch_bounds__(256) void topk_k(const float* __restrict__ S,
                                              const float* __restrict__ sq,
                                              int* __restrict__ idx) {
  const int w = threadIdx.x >> 6, lane = threadIdx.x & 63;
  const int row = blockIdx.x * 4 + w;
  const int g = row >> 8, m = row & 255;
  const float* Srow = S + (size_t)row * NM;
  const float* sqg = sq + g * NM;
  const float sm = sqg[m];
  const float4 sv = *(const float4*)&Srow[lane * 4];
  const float4 qv = *(const float4*)&sqg[lane * 4];
  float cand[4] = {sm + qv.x - 2.f * sv.x, sm + qv.y - 2.f * sv.y, sm + qv.z - 2.f * sv.z,
                   sm + qv.w - 2.f * sv.w};
#pragma unroll
  for (int t = 0; t < 4; ++t)
    if (lane * 4 + t == m) cand[t] = 1e30f;
  for (int rnd = 0; rnd < NK; ++rnd) {
    float bvv = cand[0];
    int bi = lane * 4;
#pragma unroll
    for (int t = 1; t < 4; ++t)
      if (cand[t] < bvv) {
        bvv = cand[t];
        bi = lane * 4 + t;
      }
#pragma unroll
    for (int off = 1; off < 64; off <<= 1) {
      const float ov = __shfl_xor(bvv, off);
      const int oi = __shfl_xor(bi, off);
      if (ov < bvv || (ov == bvv && oi < bi)) {
        bvv = ov;
        bi = oi;
      }
    }
    if (lane == 0) idx[(size_t)row * NK + rnd] = bi;
    if ((bi >> 2) == lane) cand[bi & 3] = 1e30f;
  }
}

// ---------------- W2 -> bf16 transposed [N=256 cols][K=256] ----------------
__global__ __launch_bounds__(256) void w2t_k(const float* __restrict__ W2,
                                             short* __restrict__ w2t) {
  const int c = blockIdx.x, k = threadIdx.x;
  w2t[c * 256 + k] = f2bf(W2[(size_t)k * 256 + c]);
}

// ---------------- edge MLP via MFMA: B(W2T) in registers, E in swizzled LDS --
// 4 waves/block; wave owns 4 col-tiles (B-frags resident in 128 VGPRs).
// Per node: cooperative E=relu(base+n1[idx]) build (bf16, XOR-swizzled, dbuf),
// then 8 x {ds_read_b128 A-frag -> 4 MFMA}. T14 split hides global latency.
__global__ __launch_bounds__(256, 2) void edgemlp_mfma2_k(
    const float* __restrict__ base, const float* __restrict__ n1, const int* __restrict__ idx,
    const short* __restrict__ w2t, const float* __restrict__ b2, float* __restrict__ feat) {
  __shared__ short E[2][16 * 256];  // 16 KB, XOR-swizzled rows
  __shared__ int sidx[NB * NK];     // 2 KB
  const int tid = threadIdx.x;
  const int l = tid & 63, wv = tid >> 6;
  const int node0 = blockIdx.x * NB;
  const int g = node0 >> 8;  // NB divides 256 -> whole block in one graph
  const int r = l & 15, gq = l >> 4;

  // preload neighbor indices for all NB nodes
  sidx[tid] = idx[(size_t)node0 * NK + tid];
  sidx[tid + 256] = idx[(size_t)node0 * NK + tid + 256];

  // preload B fragments: wave wv owns col-tiles nb = wv*4+t
  bf16x8 bfr[4][8];
  float b2v[4];
#pragma unroll
  for (int t = 0; t < 4; ++t) {
    const int nb = wv * 4 + t;
    const short* wb = w2t + (size_t)(nb * 16 + r) * 256 + gq * 8;
#pragma unroll
    for (int ks = 0; ks < 8; ++ks) bfr[t][ks] = *(const bf16x8*)(wb + ks * 32);
    b2v[t] = b2[nb * 16 + r];
  }
  __syncthreads();  // sidx visible

  // staging role: row = tid>>4 (neighbor 0..15), 16 cols per thread
  const int srow = tid >> 4, sc = (tid & 15) * 16;
  const int wbyte = ((srow * 512 + sc * 2) ^ ((srow & 7) << 4));
  f32x4 bsv[4], nsv[4];

  // stage_load(i): issue global loads for node i
  auto sload = [&](int i) {
    const float* bp = base + (((size_t)(node0 + i)) << 8) + sc;
    const float* np = n1 + ((((size_t)g << 8) + sidx[i * NK + srow]) << 8) + sc;
#pragma unroll
    for (int q = 0; q < 4; ++q) {
      bsv[q] = *(const f32x4*)(bp + q * 4);
      nsv[q] = *(const f32x4*)(np + q * 4);
    }
  };

  sload(0);
  for (int i = 0; i < NB; ++i) {
    const int buf = i & 1;
    // stage_write: relu(base+n1) -> bf16, swizzled LDS
    {
      bf16x8 w0, w1;
#pragma unroll
      for (int j = 0; j < 4; ++j) {
        w0[j] = f2bf(fmaxf(bsv[0][j] + nsv[0][j], 0.f));
        w0[j + 4] = f2bf(fmaxf(bsv[1][j] + nsv[1][j], 0.f));
        w1[j] = f2bf(fmaxf(bsv[2][j] + nsv[2][j], 0.f));
        w1[j + 4] = f2bf(fmaxf(bsv[3][j] + nsv[3][j], 0.f));
      }
      char* eb = (char*)&E[buf][0];
      *(bf16x8*)(eb + wbyte) = w0;
      *(bf16x8*)(eb + (wbyte ^ 16)) = w1;  // +16 bytes, same XOR slot family
    }
    __syncthreads();
    if (i + 1 < NB) sload(i + 1);  // issue next node's loads under compute
    // compute node i
    f32x4 acc[4];
#pragma unroll
    for (int t = 0; t < 4; ++t) acc[t] = (f32x4){0.f, 0.f, 0.f, 0.f};
    const char* eb = (const char*)&E[buf][0];
    const int abase = r * 512 + gq * 16;
#pragma unroll
    for (int ks = 0; ks < 8; ++ks) {
      const bf16x8 a = *(const bf16x8*)(eb + ((abase + ks * 64) ^ ((r & 7) << 4)));
#pragma unroll
      for (int t = 0; t < 4; ++t)
        acc[t] = __builtin_amdgcn_mfma_f32_16x16x32_bf16(a, bfr[t][ks], acc[t], 0, 0, 0);
    }
#pragma unroll
    for (int t = 0; t < 4; ++t) {
      float m1 = fmaxf(fmaxf(acc[t][0], acc[t][1]), fmaxf(acc[t][2], acc[t][3]));
      m1 = fmaxf(m1, __shfl_xor(m1, 16));
      m1 = fmaxf(m1, __shfl_xor(m1, 32));
      if (gq == 0) feat[(((size_t)(node0 + i)) << 8) + (wv * 4 + t) * 16 + r] = m1 + b2v[t];
    }
  }
}

// ---------------- Sinkhorn row normalize (axis=2), wave per row ----------------
template <bool FINAL>
__global__ __launch_bounds__(256) void sink_row_k(float* __restrict__ P) {
  const int w = threadIdx.x >> 6, lane = threadIdx.x & 63;
  const size_t row = (size_t)blockIdx.x * 4 + w;
  float* p = P + row * NM;
  float4 v = *(const float4*)&p[lane * 4];
  float mx = fmaxf(fmaxf(v.x, v.y), fmaxf(v.z, v.w));
#pragma unroll
  for (int off = 32; off; off >>= 1) mx = fmaxf(mx, __shfl_xor(mx, off));
  float s = expf(v.x - mx) + expf(v.y - mx) + expf(v.z - mx) + expf(v.w - mx);
#pragma unroll
  for (int off = 32; off; off >>= 1) s += __shfl_xor(s, off);
  const float delta = mx + logf(s) - LOGM_C;
  v.x -= delta;
  v.y -= delta;
  v.z -= delta;
  v.w -= delta;
  if (FINAL) {
    v.x = expf(v.x);
    v.y = expf(v.y);
    v.z = expf(v.z);
    v.w = expf(v.w);
  }
  *(float4*)&p[lane * 4] = v;
}

// ---------------- Sinkhorn column normalize (axis=1) ----------------
__global__ __launch_bounds__(64) void sink_col_k(float* __restrict__ P) {
  const int g = blockIdx.x;
  const int col = blockIdx.y * 64 + threadIdx.x;
  float* Pg = P + (size_t)g * NM * NM;
  float mx = -INFINITY, s = 0.f;
  for (int r2 = 0; r2 < NM; ++r2) {
    const float x = Pg[(size_t)r2 * NM + col];
    const float m2 = fmaxf(mx, x);
    s = s * expf(mx - m2) + expf(x - m2);
    mx = m2;
  }
  const float delta = mx + logf(s) - LOGM_C;
  for (int r2 = 0; r2 < NM; ++r2) Pg[(size_t)r2 * NM + col] -= delta;
}

extern "C" void kernel_launch(void* const* d_in, const int* in_sizes, int n_in, void* d_out,
                              int out_size, void* d_ws, size_t ws_size, hipStream_t stream) {
  const float* tra_x = (const float*)d_in[0];
  const float* det_x = (const float*)d_in[1];
  const float* W_enc = (const float*)d_in[2];
  const float* b_enc = (const float*)d_in[3];
  const float* W1 = (const float*)d_in[4];
  const float* b1 = (const float*)d_in[5];
  const float* W2 = (const float*)d_in[6];
  const float* b2 = (const float*)d_in[7];
  const float* eps = (const float*)d_in[8];
  float* out = (float*)d_out;

  float* ws = (float*)d_ws;
  const size_t SZ = (size_t)NR * ND;
  float* h = ws;
  float* n1b = h + SZ;
  float* baseb = n1b + SZ;
  float* featT = baseb + SZ;
  float* featD = featT + SZ;
  float* sq = featD + SZ;
  float* nT = sq + NR;
  float* nD = nT + NR;
  int* idx = (int*)(nD + NR);
  short* w2t = (short*)(idx + (size_t)NR * NK);
  float* S = out;  // gram scratch lives in d_out until the cost kernel overwrites it

  const float* xs[2] = {tra_x, det_x};
  float* feats[2] = {featT, featD};
  float* nrms[2] = {nT, nD};

  w2t_k<<<256, 256, 0, stream>>>(W2, w2t);
  for (int s2 = 0; s2 < 2; ++s2) {
    gemm_nn_k<true, true, false>
        <<<dim3(4, 256), 256, 0, stream>>>(xs[s2], W_enc, b_enc, nullptr, h, 256, 256);
    gemm_nn_k<false, false, false>
        <<<dim3(4, 256), 256, 0, stream>>>(h, W1 + 256 * 256, nullptr, nullptr, n1b, 256, 256);
    gemm_nn_k<false, true, true>
        <<<dim3(4, 256), 256, 0, stream>>>(h, W1, b1, n1b, baseb, 256, 256);
    rowsq_k<<<4096, 256, 0, stream>>>(h, sq);
    gemm_nt_k<false><<<dim3(4, 4, NG), 256, 0, stream>>>(h, h, S, nullptr, nullptr, nullptr);
    topk_k<<<4096, 256, 0, stream>>>(S, sq, idx);
    edgemlp_mfma2_k<<<NR / NB, 256, 0, stream>>>(baseb, n1b, idx, w2t, b2, feats[s2]);
    normrow_k<<<4096, 256, 0, stream>>>(feats[s2], nrms[s2]);
  }
  gemm_nt_k<true><<<dim3(4, 4, NG), 256, 0, stream>>>(featT, featD, out, nT, nD, eps);
  for (int it = 0; it < 7; ++it) {
    sink_row_k<false><<<4096, 256, 0, stream>>>(out);
    sink_col_k<<<dim3(NG, 4), 64, 0, stream>>>(out);
  }
  sink_row_k<true><<<4096, 256, 0, stream>>>(out);
}

// Round 4
// 500.165 us; speedup vs baseline: 3.9213x; 1.8314x over previous
//
#include <hip/hip_runtime.h>
#include <math.h>

#define NG 64
#define NM 256
#define ND 256
#define NK 16
#define NR (NG * NM)  // 16384 rows total
#define NB 32         // nodes per edge-MLP block

constexpr float LOGM_C = -0.10536051565782628f;  // log(0.9)

typedef __attribute__((ext_vector_type(8))) short bf16x8;
typedef __attribute__((ext_vector_type(4))) float f32x4;

static __device__ __forceinline__ short f2bf(float x) {
  union {
    float f;
    unsigned u;
  } v;
  v.f = x;
  unsigned r = v.u + 0x7FFFu + ((v.u >> 16) & 1u);
  return (short)(r >> 16);
}
static __device__ __forceinline__ float bf2f(short x) {
  union {
    unsigned u;
    float f;
  } v;
  v.u = ((unsigned)(unsigned short)x) << 16;
  return v.f;
}

// ---------------- prep: W2^T, W1cat = [W1hi - W1lo ; W1lo]^T, biascat ----------
__global__ __launch_bounds__(256) void prep_k(const float* __restrict__ W1,
                                              const float* __restrict__ b1,
                                              const float* __restrict__ W2,
                                              short* __restrict__ w2t, short* __restrict__ w1cat,
                                              float* __restrict__ biascat) {
  const int b = blockIdx.x, k = threadIdx.x;
  if (b < 256) {
    w2t[b * 256 + k] = f2bf(W2[(size_t)k * 256 + b]);
  } else {
    const int n = b - 256;  // 0..511
    float v;
    if (n < 256)
      v = W1[(size_t)k * 256 + n] - W1[(size_t)(k + 256) * 256 + n];
    else
      v = W1[(size_t)(k + 256) * 256 + (n - 256)];
    w1cat[(size_t)n * 256 + k] = f2bf(v);
    if (k == 0) biascat[n] = (n < 256) ? b1[n] : 0.f;
  }
}

// ---------------- GEMM NN fp32 (encoder): C = relu(A@B + bias), also bf16 copy --
template <bool RELU, bool BIAS, bool WBF>
__global__ __launch_bounds__(256) void gemm_nn_k(const float* __restrict__ A,
                                                 const float* __restrict__ B,
                                                 const float* __restrict__ bias,
                                                 float* __restrict__ C, short* __restrict__ Cbf,
                                                 int N, int K) {
  __shared__ float As[16][68];
  __shared__ float Bs[16][64];
  const int tid = threadIdx.x;
  const int tx = tid & 15, ty = tid >> 4;
  const int m0 = blockIdx.y * 64, n0 = blockIdx.x * 64;
  float acc[4][4] = {};
  const int ar = tid >> 2, akc = (tid & 3) * 4;
  const int bkr = tid >> 4, bc = (tid & 15) * 4;
  for (int k0 = 0; k0 < K; k0 += 16) {
    float4 av = *(const float4*)&A[(size_t)(m0 + ar) * K + k0 + akc];
    As[akc + 0][ar] = av.x;
    As[akc + 1][ar] = av.y;
    As[akc + 2][ar] = av.z;
    As[akc + 3][ar] = av.w;
    *(float4*)&Bs[bkr][bc] = *(const float4*)&B[(size_t)(k0 + bkr) * N + n0 + bc];
    __syncthreads();
#pragma unroll
    for (int kk = 0; kk < 16; ++kk) {
      const float4 a = *(const float4*)&As[kk][ty * 4];
      const float4 b = *(const float4*)&Bs[kk][tx * 4];
      const float aa[4] = {a.x, a.y, a.z, a.w};
      const float bb[4] = {b.x, b.y, b.z, b.w};
#pragma unroll
      for (int i = 0; i < 4; ++i)
#pragma unroll
        for (int j = 0; j < 4; ++j) acc[i][j] = fmaf(aa[i], bb[j], acc[i][j]);
    }
    __syncthreads();
  }
  float4 bv = {0.f, 0.f, 0.f, 0.f};
  if (BIAS) bv = *(const float4*)&bias[n0 + tx * 4];
#pragma unroll
  for (int i = 0; i < 4; ++i) {
    float4 o = {acc[i][0], acc[i][1], acc[i][2], acc[i][3]};
    if (BIAS) {
      o.x += bv.x;
      o.y += bv.y;
      o.z += bv.z;
      o.w += bv.w;
    }
    if (RELU) {
      o.x = fmaxf(o.x, 0.f);
      o.y = fmaxf(o.y, 0.f);
      o.z = fmaxf(o.z, 0.f);
      o.w = fmaxf(o.w, 0.f);
    }
    const size_t off = (size_t)(m0 + ty * 4 + i) * N + n0 + tx * 4;
    *(float4*)&C[off] = o;
    if (WBF) {
      short4 hb = {f2bf(o.x), f2bf(o.y), f2bf(o.z), f2bf(o.w)};
      *(short4*)&Cbf[off] = hb;
    }
  }
}

// ---------------- batched GEMM NT fp32 per graph (gram, selection path) -------
__global__ __launch_bounds__(256) void gemm_nt_k(const float* __restrict__ A,
                                                 const float* __restrict__ B,
                                                 float* __restrict__ C) {
  __shared__ float As[16][68];
  __shared__ float Bs[16][68];
  const int g = blockIdx.z;
  const float* Ag = A + (size_t)g * NM * ND;
  const float* Bg = B + (size_t)g * NM * ND;
  const int tid = threadIdx.x;
  const int tx = tid & 15, ty = tid >> 4;
  const int m0 = blockIdx.y * 64, n0 = blockIdx.x * 64;
  float acc[4][4] = {};
  const int r = tid >> 2, kc = (tid & 3) * 4;
  for (int k0 = 0; k0 < ND; k0 += 16) {
    float4 av = *(const float4*)&Ag[(size_t)(m0 + r) * ND + k0 + kc];
    As[kc + 0][r] = av.x;
    As[kc + 1][r] = av.y;
    As[kc + 2][r] = av.z;
    As[kc + 3][r] = av.w;
    float4 bvv = *(const float4*)&Bg[(size_t)(n0 + r) * ND + k0 + kc];
    Bs[kc + 0][r] = bvv.x;
    Bs[kc + 1][r] = bvv.y;
    Bs[kc + 2][r] = bvv.z;
    Bs[kc + 3][r] = bvv.w;
    __syncthreads();
#pragma unroll
    for (int kk = 0; kk < 16; ++kk) {
      const float4 a = *(const float4*)&As[kk][ty * 4];
      const float4 b = *(const float4*)&Bs[kk][tx * 4];
      const float aa[4] = {a.x, a.y, a.z, a.w};
      const float bb[4] = {b.x, b.y, b.z, b.w};
#pragma unroll
      for (int i = 0; i < 4; ++i)
#pragma unroll
        for (int j = 0; j < 4; ++j) acc[i][j] = fmaf(aa[i], bb[j], acc[i][j]);
    }
    __syncthreads();
  }
#pragma unroll
  for (int i = 0; i < 4; ++i) {
    const int m = m0 + ty * 4 + i;
    float4 o = {acc[i][0], acc[i][1], acc[i][2], acc[i][3]};
    *(float4*)&C[(size_t)g * NM * NM + (size_t)m * NM + n0 + tx * 4] = o;
  }
}

// ---------------- MFMA GEMM: [16384,256]bf16 @ w1cat^T -> baseb, n1b (bf16) ---
__global__ __launch_bounds__(256, 2) void mlp1_mfma_k(const short* __restrict__ A,
                                                      const short* __restrict__ Bt,
                                                      const float* __restrict__ biascat,
                                                      short* __restrict__ baseb,
                                                      short* __restrict__ n1b) {
  __shared__ char As[64 * 512];
  const int tid = threadIdx.x;
  const int l = tid & 63, wv = tid >> 6;
  const int r = l & 15, gq = l >> 4;
  const int m0 = blockIdx.y * 64, n0 = blockIdx.x * 128;
  // B-fragments in registers: wave owns cols n0 + wv*32 + nt*16 + r
  bf16x8 bfr[2][8];
  float bv[2];
#pragma unroll
  for (int nt = 0; nt < 2; ++nt) {
    const int col = n0 + wv * 32 + nt * 16 + r;
    const short* wb = Bt + (size_t)col * 256 + gq * 8;
#pragma unroll
    for (int ks = 0; ks < 8; ++ks) bfr[nt][ks] = *(const bf16x8*)(wb + ks * 32);
    bv[nt] = biascat[col];
  }
  // stage A (bf16) into swizzled LDS
  const int row = tid >> 2, ch = tid & 3;
  const char* ag = (const char*)(A + (size_t)(m0 + row) * 256) + ch * 128;
  char* lb = As + row * 512;
#pragma unroll
  for (int j = 0; j < 8; ++j)
    *(bf16x8*)(lb + (((ch * 128 + j * 16)) ^ ((row & 7) << 4))) = *(const bf16x8*)(ag + j * 16);
  __syncthreads();
  f32x4 acc[4][2];
#pragma unroll
  for (int mt = 0; mt < 4; ++mt)
#pragma unroll
    for (int nt = 0; nt < 2; ++nt) acc[mt][nt] = (f32x4){0.f, 0.f, 0.f, 0.f};
#pragma unroll
  for (int ks = 0; ks < 8; ++ks) {
    bf16x8 a[4];
#pragma unroll
    for (int mt = 0; mt < 4; ++mt)
      a[mt] = *(const bf16x8*)(As + (mt * 16 + r) * 512 + ((gq * 16 + ks * 64) ^ ((r & 7) << 4)));
#pragma unroll
    for (int mt = 0; mt < 4; ++mt)
#pragma unroll
      for (int nt = 0; nt < 2; ++nt)
        acc[mt][nt] = __builtin_amdgcn_mfma_f32_16x16x32_bf16(a[mt], bfr[nt][ks], acc[mt][nt], 0, 0, 0);
  }
  short* dst = (n0 < 256) ? baseb : n1b;
  const int cb = (n0 < 256) ? n0 : n0 - 256;
#pragma unroll
  for (int mt = 0; mt < 4; ++mt)
#pragma unroll
    for (int nt = 0; nt < 2; ++nt) {
      const int col = cb + wv * 32 + nt * 16 + r;
#pragma unroll
      for (int reg = 0; reg < 4; ++reg) {
        const int rw = m0 + mt * 16 + gq * 4 + reg;
        dst[(size_t)rw * 256 + col] = f2bf(acc[mt][nt][reg] + bv[nt]);
      }
    }
}

// ---------------- MFMA cost GEMM: P = (featT@featD^T) /(nA nB lam), batched ----
__global__ __launch_bounds__(256, 2) void cost_mfma_k(const short* __restrict__ featT,
                                                      const short* __restrict__ featD,
                                                      const float* __restrict__ nA,
                                                      const float* __restrict__ nB,
                                                      const float* __restrict__ eps,
                                                      float* __restrict__ P) {
  __shared__ char As[64 * 512];
  const int g = blockIdx.z;
  const short* A = featT + (size_t)g * NM * ND;
  const short* Bt = featD + (size_t)g * NM * ND;
  const int tid = threadIdx.x;
  const int l = tid & 63, wv = tid >> 6;
  const int r = l & 15, gq = l >> 4;
  const int m0 = blockIdx.y * 64, n0 = blockIdx.x * 128;
  bf16x8 bfr[2][8];
  float rnb[2];
#pragma unroll
  for (int nt = 0; nt < 2; ++nt) {
    const int col = n0 + wv * 32 + nt * 16 + r;
    const short* wb = Bt + (size_t)col * 256 + gq * 8;
#pragma unroll
    for (int ks = 0; ks < 8; ++ks) bfr[nt][ks] = *(const bf16x8*)(wb + ks * 32);
    rnb[nt] = 1.0f / nB[g * NM + col];
  }
  const int row = tid >> 2, ch = tid & 3;
  const char* ag = (const char*)(A + (size_t)(m0 + row) * 256) + ch * 128;
  char* lb = As + row * 512;
#pragma unroll
  for (int j = 0; j < 8; ++j)
    *(bf16x8*)(lb + (((ch * 128 + j * 16)) ^ ((row & 7) << 4))) = *(const bf16x8*)(ag + j * 16);
  __syncthreads();
  f32x4 acc[4][2];
#pragma unroll
  for (int mt = 0; mt < 4; ++mt)
#pragma unroll
    for (int nt = 0; nt < 2; ++nt) acc[mt][nt] = (f32x4){0.f, 0.f, 0.f, 0.f};
#pragma unroll
  for (int ks = 0; ks < 8; ++ks) {
    bf16x8 a[4];
#pragma unroll
    for (int mt = 0; mt < 4; ++mt)
      a[mt] = *(const bf16x8*)(As + (mt * 16 + r) * 512 + ((gq * 16 + ks * 64) ^ ((r & 7) << 4)));
#pragma unroll
    for (int mt = 0; mt < 4; ++mt)
#pragma unroll
      for (int nt = 0; nt < 2; ++nt)
        acc[mt][nt] = __builtin_amdgcn_mfma_f32_16x16x32_bf16(a[mt], bfr[nt][ks], acc[mt][nt], 0, 0, 0);
  }
  const float inv_lam = 1.0f / (expf(eps[0]) + 0.03f);
#pragma unroll
  for (int mt = 0; mt < 4; ++mt) {
    float ria[4];
#pragma unroll
    for (int reg = 0; reg < 4; ++reg)
      ria[reg] = inv_lam / nA[g * NM + m0 + mt * 16 + gq * 4 + reg];
#pragma unroll
    for (int nt = 0; nt < 2; ++nt) {
      const int col = n0 + wv * 32 + nt * 16 + r;
#pragma unroll
      for (int reg = 0; reg < 4; ++reg) {
        const int rw = m0 + mt * 16 + gq * 4 + reg;
        P[(size_t)g * NM * NM + (size_t)rw * 256 + col] = acc[mt][nt][reg] * ria[reg] * rnb[nt];
      }
    }
  }
}

// ---------------- per-row sum of squares (fp32 h) ----------------
__global__ __launch_bounds__(256) void rowsq_k(const float* __restrict__ h,
                                               float* __restrict__ sq) {
  const int w = threadIdx.x >> 6, lane = threadIdx.x & 63;
  const int row = blockIdx.x * 4 + w;
  float4 v = *(const float4*)&h[(size_t)row * ND + lane * 4];
  float s = v.x * v.x + v.y * v.y + v.z * v.z + v.w * v.w;
#pragma unroll
  for (int off = 32; off; off >>= 1) s += __shfl_xor(s, off);
  if (lane == 0) sq[row] = s;
}

// ---------------- per-row L2 norm of bf16 feat ----------------
__global__ __launch_bounds__(256) void normrow_bf_k(const short* __restrict__ feat,
                                                    float* __restrict__ nrm) {
  const int w = threadIdx.x >> 6, lane = threadIdx.x & 63;
  const int row = blockIdx.x * 4 + w;
  const short4 v = *(const short4*)&feat[(size_t)row * ND + lane * 4];
  const float a = bf2f(v.x), b = bf2f(v.y), c = bf2f(v.z), d = bf2f(v.w);
  float s = a * a + b * b + c * c + d * d;
#pragma unroll
  for (int off = 32; off; off >>= 1) s += __shfl_xor(s, off);
  if (lane == 0) nrm[row] = sqrtf(s);
}

// ---------------- top-16 nearest neighbors (wave per row) ----------------
__global__ __launch_bounds__(256) void topk_k(const float* __restrict__ S,
                                              const float* __restrict__ sq,
                                              int* __restrict__ idx) {
  const int w = threadIdx.x >> 6, lane = threadIdx.x & 63;
  const int row = blockIdx.x * 4 + w;
  const int g = row >> 8, m = row & 255;
  const float* Srow = S + (size_t)row * NM;
  const float* sqg = sq + g * NM;
  const float sm = sqg[m];
  const float4 sv = *(const float4*)&Srow[lane * 4];
  const float4 qv = *(const float4*)&sqg[lane * 4];
  float cand[4] = {sm + qv.x - 2.f * sv.x, sm + qv.y - 2.f * sv.y, sm + qv.z - 2.f * sv.z,
                   sm + qv.w - 2.f * sv.w};
#pragma unroll
  for (int t = 0; t < 4; ++t)
    if (lane * 4 + t == m) cand[t] = 1e30f;
  for (int rnd = 0; rnd < NK; ++rnd) {
    float bvv = cand[0];
    int bi = lane * 4;
#pragma unroll
    for (int t = 1; t < 4; ++t)
      if (cand[t] < bvv) {
        bvv = cand[t];
        bi = lane * 4 + t;
      }
#pragma unroll
    for (int off = 1; off < 64; off <<= 1) {
      const float ov = __shfl_xor(bvv, off);
      const int oi = __shfl_xor(bi, off);
      if (ov < bvv || (ov == bvv && oi < bi)) {
        bvv = ov;
        bi = oi;
      }
    }
    if (lane == 0) idx[(size_t)row * NK + rnd] = bi;
    if ((bi >> 2) == lane) cand[bi & 3] = 1e30f;
  }
}

// ---------------- edge MLP via MFMA, 8 waves, bf16 in/out ----------------
__global__ __launch_bounds__(512, 4) void edgemlp_mfma3_k(
    const short* __restrict__ baseb, const short* __restrict__ n1b, const int* __restrict__ idx,
    const short* __restrict__ w2t, const float* __restrict__ b2, short* __restrict__ featbf) {
  __shared__ short E[2][16 * 256];  // 16 KB, XOR-swizzled rows
  __shared__ int sidx[NB * NK];     // 512 ints
  const int tid = threadIdx.x;
  const int l = tid & 63, wv = tid >> 6;
  const int node0 = blockIdx.x * NB;
  const int g = node0 >> 8;
  const int r = l & 15, gq = l >> 4;
  sidx[tid] = idx[(size_t)node0 * NK + tid];
  // B fragments: wave owns col-tiles nb = wv*2 + t
  bf16x8 bfr[2][8];
  float b2v[2];
#pragma unroll
  for (int t = 0; t < 2; ++t) {
    const int nb = wv * 2 + t;
    const short* wb = w2t + (size_t)(nb * 16 + r) * 256 + gq * 8;
#pragma unroll
    for (int ks = 0; ks < 8; ++ks) bfr[t][ks] = *(const bf16x8*)(wb + ks * 32);
    b2v[t] = b2[nb * 16 + r];
  }
  __syncthreads();  // sidx visible
  const int srow = tid >> 5, sc = (tid & 31) * 8;
  const int wbyte = ((srow * 512 + sc * 2) ^ ((srow & 7) << 4));
  bf16x8 bs, ns;
  auto sload = [&](int i) {
    bs = *(const bf16x8*)(baseb + (((size_t)(node0 + i)) << 8) + sc);
    ns = *(const bf16x8*)(n1b + ((((size_t)g << 8) + sidx[i * NK + srow]) << 8) + sc);
  };
  sload(0);
  for (int i = 0; i < NB; ++i) {
    const int buf = i & 1;
    bf16x8 w0;
#pragma unroll
    for (int j = 0; j < 8; ++j) w0[j] = f2bf(fmaxf(bf2f(bs[j]) + bf2f(ns[j]), 0.f));
    *(bf16x8*)((char*)&E[buf][0] + wbyte) = w0;
    __syncthreads();
    if (i + 1 < NB) sload(i + 1);
    f32x4 acc[2];
    acc[0] = (f32x4){0.f, 0.f, 0.f, 0.f};
    acc[1] = (f32x4){0.f, 0.f, 0.f, 0.f};
    const char* eb = (const char*)&E[buf][0];
    const int abase = r * 512 + gq * 16;
#pragma unroll
    for (int ks = 0; ks < 8; ++ks) {
      const bf16x8 a = *(const bf16x8*)(eb + ((abase + ks * 64) ^ ((r & 7) << 4)));
      acc[0] = __builtin_amdgcn_mfma_f32_16x16x32_bf16(a, bfr[0][ks], acc[0], 0, 0, 0);
      acc[1] = __builtin_amdgcn_mfma_f32_16x16x32_bf16(a, bfr[1][ks], acc[1], 0, 0, 0);
    }
#pragma unroll
    for (int t = 0; t < 2; ++t) {
      float m1 = fmaxf(fmaxf(acc[t][0], acc[t][1]), fmaxf(acc[t][2], acc[t][3]));
      m1 = fmaxf(m1, __shfl_xor(m1, 16));
      m1 = fmaxf(m1, __shfl_xor(m1, 32));
      if (gq == 0)
        featbf[(((size_t)(node0 + i)) << 8) + (wv * 2 + t) * 16 + r] = f2bf(m1 + b2v[t]);
    }
  }
}

// ---------------- fused Sinkhorn: one block per graph, P in registers --------
__global__ __launch_bounds__(1024) void sinkhorn_k(float* __restrict__ P) {
  __shared__ float red[16][256];
  __shared__ float delta[256];
  const int t = threadIdx.x;
  const int tc = t & 15;   // cols tc*16 .. +15
  const int trw = t >> 4;  // rows trw*4 .. +3
  const int wv = t >> 6, l = t & 63;
  float* Pg = P + (size_t)blockIdx.x * NM * NM;
  float p[4][16];
#pragma unroll
  for (int i = 0; i < 4; ++i)
#pragma unroll
    for (int q = 0; q < 4; ++q)
      *(f32x4*)&p[i][q * 4] = *(const f32x4*)&Pg[(size_t)(trw * 4 + i) * NM + tc * 16 + q * 4];

  auto rowpass = [&]() {
#pragma unroll
    for (int i = 0; i < 4; ++i) {
      float mx = p[i][0];
#pragma unroll
      for (int j = 1; j < 16; ++j) mx = fmaxf(mx, p[i][j]);
      mx = fmaxf(mx, __shfl_xor(mx, 1));
      mx = fmaxf(mx, __shfl_xor(mx, 2));
      mx = fmaxf(mx, __shfl_xor(mx, 4));
      mx = fmaxf(mx, __shfl_xor(mx, 8));
      float s = 0.f;
#pragma unroll
      for (int j = 0; j < 16; ++j) s += expf(p[i][j] - mx);
      s += __shfl_xor(s, 1);
      s += __shfl_xor(s, 2);
      s += __shfl_xor(s, 4);
      s += __shfl_xor(s, 8);
      const float d = mx + logf(s) - LOGM_C;
#pragma unroll
      for (int j = 0; j < 16; ++j) p[i][j] -= d;
    }
  };
  auto colpass = [&]() {
    float tmp[16];
#pragma unroll
    for (int j = 0; j < 16; ++j)
      tmp[j] = fmaxf(fmaxf(p[0][j], p[1][j]), fmaxf(p[2][j], p[3][j]));
#pragma unroll
    for (int j = 0; j < 16; ++j) {
      tmp[j] = fmaxf(tmp[j], __shfl_xor(tmp[j], 16));
      tmp[j] = fmaxf(tmp[j], __shfl_xor(tmp[j], 32));
    }
    if (l < 16) {
#pragma unroll
      for (int j = 0; j < 16; ++j) red[wv][l * 16 + j] = tmp[j];
    }
    __syncthreads();
    if (t < 256) {
      float m = red[0][t];
#pragma unroll
      for (int w = 1; w < 16; ++w) m = fmaxf(m, red[w][t]);
      delta[t] = m;
    }
    __syncthreads();
#pragma unroll
    for (int j = 0; j < 16; ++j) {
      const float cm = delta[tc * 16 + j];
      tmp[j] = expf(p[0][j] - cm) + expf(p[1][j] - cm) + expf(p[2][j] - cm) + expf(p[3][j] - cm);
    }
#pragma unroll
    for (int j = 0; j < 16; ++j) {
      tmp[j] += __shfl_xor(tmp[j], 16);
      tmp[j] += __shfl_xor(tmp[j], 32);
    }
    if (l < 16) {
#pragma unroll
      for (int j = 0; j < 16; ++j) red[wv][l * 16 + j] = tmp[j];
    }
    __syncthreads();
    if (t < 256) {
      float s = 0.f;
#pragma unroll
      for (int w = 0; w < 16; ++w) s += red[w][t];
      delta[t] = delta[t] + logf(s) - LOGM_C;
    }
    __syncthreads();
#pragma unroll
    for (int j = 0; j < 16; ++j) {
      const float d = delta[tc * 16 + j];
#pragma unroll
      for (int i = 0; i < 4; ++i) p[i][j] -= d;
    }
  };
  for (int it = 0; it < 7; ++it) {
    rowpass();
    colpass();
  }
  rowpass();
#pragma unroll
  for (int i = 0; i < 4; ++i)
#pragma unroll
    for (int j = 0; j < 16; ++j) p[i][j] = expf(p[i][j]);
#pragma unroll
  for (int i = 0; i < 4; ++i)
#pragma unroll
    for (int q = 0; q < 4; ++q)
      *(f32x4*)&Pg[(size_t)(trw * 4 + i) * NM + tc * 16 + q * 4] = *(const f32x4*)&p[i][q * 4];
}

extern "C" void kernel_launch(void* const* d_in, const int* in_sizes, int n_in, void* d_out,
                              int out_size, void* d_ws, size_t ws_size, hipStream_t stream) {
  const float* tra_x = (const float*)d_in[0];
  const float* det_x = (const float*)d_in[1];
  const float* W_enc = (const float*)d_in[2];
  const float* b_enc = (const float*)d_in[3];
  const float* W1 = (const float*)d_in[4];
  const float* b1 = (const float*)d_in[5];
  const float* W2 = (const float*)d_in[6];
  const float* b2 = (const float*)d_in[7];
  const float* eps = (const float*)d_in[8];
  float* out = (float*)d_out;

  const size_t SZ = (size_t)NR * ND;
  float* h = (float*)d_ws;
  short* hbf = (short*)(h + SZ);
  short* baseb = hbf + SZ;
  short* n1b = baseb + SZ;
  short* featT = n1b + SZ;
  short* featD = featT + SZ;
  float* sq = (float*)(featD + SZ);
  float* nT = sq + NR;
  float* nD = nT + NR;
  int* idx = (int*)(nD + NR);
  short* w2t = (short*)(idx + (size_t)NR * NK);
  short* w1cat = w2t + 256 * 256;
  float* biascat = (float*)(w1cat + 512 * 256);
  float* S = out;  // gram scratch lives in d_out until cost overwrites it

  const float* xs[2] = {tra_x, det_x};
  short* feats[2] = {featT, featD};
  float* nrms[2] = {nT, nD};

  prep_k<<<768, 256, 0, stream>>>(W1, b1, W2, w2t, w1cat, biascat);
  for (int s2 = 0; s2 < 2; ++s2) {
    gemm_nn_k<true, true, true>
        <<<dim3(4, 256), 256, 0, stream>>>(xs[s2], W_enc, b_enc, h, hbf, 256, 256);
    mlp1_mfma_k<<<dim3(4, 256), 256, 0, stream>>>(hbf, w1cat, biascat, baseb, n1b);
    rowsq_k<<<4096, 256, 0, stream>>>(h, sq);
    gemm_nt_k<<<dim3(4, 4, NG), 256, 0, stream>>>(h, h, S);
    topk_k<<<4096, 256, 0, stream>>>(S, sq, idx);
    edgemlp_mfma3_k<<<NR / NB, 512, 0, stream>>>(baseb, n1b, idx, w2t, b2, feats[s2]);
    normrow_bf_k<<<4096, 256, 0, stream>>>(feats[s2], nrms[s2]);
  }
  cost_mfma_k<<<dim3(2, 4, NG), 256, 0, stream>>>(featT, featD, nT, nD, eps, out);
  sinkhorn_k<<<NG, 1024, 0, stream>>>(out);
}

// Round 5
// 401.283 us; speedup vs baseline: 4.8876x; 1.2464x over previous
//
#include <hip/hip_runtime.h>
#include <math.h>

#define NG 64
#define NM 256
#define ND 256
#define NK 16
#define NR (NG * NM)  // 16384 rows total
#define NB 32         // nodes per edge-MLP block

#define MASSF 0.9f

typedef __attribute__((ext_vector_type(8))) short bf16x8;
typedef __attribute__((ext_vector_type(4))) float f32x4;

static __device__ __forceinline__ short f2bf(float x) {
  union {
    float f;
    unsigned u;
  } v;
  v.f = x;
  unsigned r = v.u + 0x7FFFu + ((v.u >> 16) & 1u);
  return (short)(r >> 16);
}
static __device__ __forceinline__ float bf2f(short x) {
  union {
    unsigned u;
    float f;
  } v;
  v.u = ((unsigned)(unsigned short)x) << 16;
  return v.f;
}

// ---------------- prep: W2^T, W1cat = [W1hi - W1lo ; W1lo]^T, biascat ----------
__global__ __launch_bounds__(256) void prep_k(const float* __restrict__ W1,
                                              const float* __restrict__ b1,
                                              const float* __restrict__ W2,
                                              short* __restrict__ w2t, short* __restrict__ w1cat,
                                              float* __restrict__ biascat) {
  const int b = blockIdx.x, k = threadIdx.x;
  if (b < 256) {
    w2t[b * 256 + k] = f2bf(W2[(size_t)k * 256 + b]);
  } else {
    const int n = b - 256;  // 0..511
    float v;
    if (n < 256)
      v = W1[(size_t)k * 256 + n] - W1[(size_t)(k + 256) * 256 + n];
    else
      v = W1[(size_t)(k + 256) * 256 + (n - 256)];
    w1cat[(size_t)n * 256 + k] = f2bf(v);
    if (k == 0) biascat[n] = (n < 256) ? b1[n] : 0.f;
  }
}

// ---------------- GEMM NN fp32 (encoder): C = relu(A@B + bias), also bf16 copy --
template <bool RELU, bool BIAS, bool WBF>
__global__ __launch_bounds__(256) void gemm_nn_k(const float* __restrict__ A,
                                                 const float* __restrict__ B,
                                                 const float* __restrict__ bias,
                                                 float* __restrict__ C, short* __restrict__ Cbf,
                                                 int N, int K) {
  __shared__ float As[16][68];
  __shared__ float Bs[16][64];
  const int tid = threadIdx.x;
  const int tx = tid & 15, ty = tid >> 4;
  const int m0 = blockIdx.y * 64, n0 = blockIdx.x * 64;
  float acc[4][4] = {};
  const int ar = tid >> 2, akc = (tid & 3) * 4;
  const int bkr = tid >> 4, bc = (tid & 15) * 4;
  for (int k0 = 0; k0 < K; k0 += 16) {
    float4 av = *(const float4*)&A[(size_t)(m0 + ar) * K + k0 + akc];
    As[akc + 0][ar] = av.x;
    As[akc + 1][ar] = av.y;
    As[akc + 2][ar] = av.z;
    As[akc + 3][ar] = av.w;
    *(float4*)&Bs[bkr][bc] = *(const float4*)&B[(size_t)(k0 + bkr) * N + n0 + bc];
    __syncthreads();
#pragma unroll
    for (int kk = 0; kk < 16; ++kk) {
      const float4 a = *(const float4*)&As[kk][ty * 4];
      const float4 b = *(const float4*)&Bs[kk][tx * 4];
      const float aa[4] = {a.x, a.y, a.z, a.w};
      const float bb[4] = {b.x, b.y, b.z, b.w};
#pragma unroll
      for (int i = 0; i < 4; ++i)
#pragma unroll
        for (int j = 0; j < 4; ++j) acc[i][j] = fmaf(aa[i], bb[j], acc[i][j]);
    }
    __syncthreads();
  }
  float4 bv = {0.f, 0.f, 0.f, 0.f};
  if (BIAS) bv = *(const float4*)&bias[n0 + tx * 4];
#pragma unroll
  for (int i = 0; i < 4; ++i) {
    float4 o = {acc[i][0], acc[i][1], acc[i][2], acc[i][3]};
    if (BIAS) {
      o.x += bv.x;
      o.y += bv.y;
      o.z += bv.z;
      o.w += bv.w;
    }
    if (RELU) {
      o.x = fmaxf(o.x, 0.f);
      o.y = fmaxf(o.y, 0.f);
      o.z = fmaxf(o.z, 0.f);
      o.w = fmaxf(o.w, 0.f);
    }
    const size_t off = (size_t)(m0 + ty * 4 + i) * N + n0 + tx * 4;
    *(float4*)&C[off] = o;
    if (WBF) {
      short4 hb = {f2bf(o.x), f2bf(o.y), f2bf(o.z), f2bf(o.w)};
      *(short4*)&Cbf[off] = hb;
    }
  }
}

// ---------------- batched GEMM NT fp32 per graph (gram, selection path) -------
__global__ __launch_bounds__(256) void gemm_nt_k(const float* __restrict__ A,
                                                 const float* __restrict__ B,
                                                 float* __restrict__ C) {
  __shared__ float As[16][68];
  __shared__ float Bs[16][68];
  const int g = blockIdx.z;
  const float* Ag = A + (size_t)g * NM * ND;
  const float* Bg = B + (size_t)g * NM * ND;
  const int tid = threadIdx.x;
  const int tx = tid & 15, ty = tid >> 4;
  const int m0 = blockIdx.y * 64, n0 = blockIdx.x * 64;
  float acc[4][4] = {};
  const int r = tid >> 2, kc = (tid & 3) * 4;
  for (int k0 = 0; k0 < ND; k0 += 16) {
    float4 av = *(const float4*)&Ag[(size_t)(m0 + r) * ND + k0 + kc];
    As[kc + 0][r] = av.x;
    As[kc + 1][r] = av.y;
    As[kc + 2][r] = av.z;
    As[kc + 3][r] = av.w;
    float4 bvv = *(const float4*)&Bg[(size_t)(n0 + r) * ND + k0 + kc];
    Bs[kc + 0][r] = bvv.x;
    Bs[kc + 1][r] = bvv.y;
    Bs[kc + 2][r] = bvv.z;
    Bs[kc + 3][r] = bvv.w;
    __syncthreads();
#pragma unroll
    for (int kk = 0; kk < 16; ++kk) {
      const float4 a = *(const float4*)&As[kk][ty * 4];
      const float4 b = *(const float4*)&Bs[kk][tx * 4];
      const float aa[4] = {a.x, a.y, a.z, a.w};
      const float bb[4] = {b.x, b.y, b.z, b.w};
#pragma unroll
      for (int i = 0; i < 4; ++i)
#pragma unroll
        for (int j = 0; j < 4; ++j) acc[i][j] = fmaf(aa[i], bb[j], acc[i][j]);
    }
    __syncthreads();
  }
#pragma unroll
  for (int i = 0; i < 4; ++i) {
    const int m = m0 + ty * 4 + i;
    float4 o = {acc[i][0], acc[i][1], acc[i][2], acc[i][3]};
    *(float4*)&C[(size_t)g * NM * NM + (size_t)m * NM + n0 + tx * 4] = o;
  }
}

// ---------------- MFMA GEMM: [16384,256]bf16 @ w1cat^T -> baseb, n1b (bf16) ---
__global__ __launch_bounds__(256, 2) void mlp1_mfma_k(const short* __restrict__ A,
                                                      const short* __restrict__ Bt,
                                                      const float* __restrict__ biascat,
                                                      short* __restrict__ baseb,
                                                      short* __restrict__ n1b) {
  __shared__ char As[64 * 512];
  const int tid = threadIdx.x;
  const int l = tid & 63, wv = tid >> 6;
  const int r = l & 15, gq = l >> 4;
  const int m0 = blockIdx.y * 64, n0 = blockIdx.x * 128;
  bf16x8 bfr[2][8];
  float bv[2];
#pragma unroll
  for (int nt = 0; nt < 2; ++nt) {
    const int col = n0 + wv * 32 + nt * 16 + r;
    const short* wb = Bt + (size_t)col * 256 + gq * 8;
#pragma unroll
    for (int ks = 0; ks < 8; ++ks) bfr[nt][ks] = *(const bf16x8*)(wb + ks * 32);
    bv[nt] = biascat[col];
  }
  const int row = tid >> 2, ch = tid & 3;
  const char* ag = (const char*)(A + (size_t)(m0 + row) * 256) + ch * 128;
  char* lb = As + row * 512;
#pragma unroll
  for (int j = 0; j < 8; ++j)
    *(bf16x8*)(lb + (((ch * 128 + j * 16)) ^ ((row & 7) << 4))) = *(const bf16x8*)(ag + j * 16);
  __syncthreads();
  f32x4 acc[4][2];
#pragma unroll
  for (int mt = 0; mt < 4; ++mt)
#pragma unroll
    for (int nt = 0; nt < 2; ++nt) acc[mt][nt] = (f32x4){0.f, 0.f, 0.f, 0.f};
#pragma unroll
  for (int ks = 0; ks < 8; ++ks) {
    bf16x8 a[4];
#pragma unroll
    for (int mt = 0; mt < 4; ++mt)
      a[mt] = *(const bf16x8*)(As + (mt * 16 + r) * 512 + ((gq * 16 + ks * 64) ^ ((r & 7) << 4)));
#pragma unroll
    for (int mt = 0; mt < 4; ++mt)
#pragma unroll
      for (int nt = 0; nt < 2; ++nt)
        acc[mt][nt] = __builtin_amdgcn_mfma_f32_16x16x32_bf16(a[mt], bfr[nt][ks], acc[mt][nt], 0, 0, 0);
  }
  short* dst = (n0 < 256) ? baseb : n1b;
  const int cb = (n0 < 256) ? n0 : n0 - 256;
#pragma unroll
  for (int mt = 0; mt < 4; ++mt)
#pragma unroll
    for (int nt = 0; nt < 2; ++nt) {
      const int col = cb + wv * 32 + nt * 16 + r;
#pragma unroll
      for (int reg = 0; reg < 4; ++reg) {
        const int rw = m0 + mt * 16 + gq * 4 + reg;
        dst[(size_t)rw * 256 + col] = f2bf(acc[mt][nt][reg] + bv[nt]);
      }
    }
}

// ---------------- MFMA cost GEMM -> P0 = exp(corr/(nA nB lam)), batched --------
__global__ __launch_bounds__(256, 2) void cost_mfma_k(const short* __restrict__ featT,
                                                      const short* __restrict__ featD,
                                                      const float* __restrict__ nA,
                                                      const float* __restrict__ nB,
                                                      const float* __restrict__ eps,
                                                      float* __restrict__ P) {
  __shared__ char As[64 * 512];
  const int g = blockIdx.z;
  const short* A = featT + (size_t)g * NM * ND;
  const short* Bt = featD + (size_t)g * NM * ND;
  const int tid = threadIdx.x;
  const int l = tid & 63, wv = tid >> 6;
  const int r = l & 15, gq = l >> 4;
  const int m0 = blockIdx.y * 64, n0 = blockIdx.x * 128;
  bf16x8 bfr[2][8];
  float rnb[2];
#pragma unroll
  for (int nt = 0; nt < 2; ++nt) {
    const int col = n0 + wv * 32 + nt * 16 + r;
    const short* wb = Bt + (size_t)col * 256 + gq * 8;
#pragma unroll
    for (int ks = 0; ks < 8; ++ks) bfr[nt][ks] = *(const bf16x8*)(wb + ks * 32);
    rnb[nt] = 1.0f / nB[g * NM + col];
  }
  const int row = tid >> 2, ch = tid & 3;
  const char* ag = (const char*)(A + (size_t)(m0 + row) * 256) + ch * 128;
  char* lb = As + row * 512;
#pragma unroll
  for (int j = 0; j < 8; ++j)
    *(bf16x8*)(lb + (((ch * 128 + j * 16)) ^ ((row & 7) << 4))) = *(const bf16x8*)(ag + j * 16);
  __syncthreads();
  f32x4 acc[4][2];
#pragma unroll
  for (int mt = 0; mt < 4; ++mt)
#pragma unroll
    for (int nt = 0; nt < 2; ++nt) acc[mt][nt] = (f32x4){0.f, 0.f, 0.f, 0.f};
#pragma unroll
  for (int ks = 0; ks < 8; ++ks) {
    bf16x8 a[4];
#pragma unroll
    for (int mt = 0; mt < 4; ++mt)
      a[mt] = *(const bf16x8*)(As + (mt * 16 + r) * 512 + ((gq * 16 + ks * 64) ^ ((r & 7) << 4)));
#pragma unroll
    for (int mt = 0; mt < 4; ++mt)
#pragma unroll
      for (int nt = 0; nt < 2; ++nt)
        acc[mt][nt] = __builtin_amdgcn_mfma_f32_16x16x32_bf16(a[mt], bfr[nt][ks], acc[mt][nt], 0, 0, 0);
  }
  const float inv_lam = 1.0f / (expf(eps[0]) + 0.03f);
#pragma unroll
  for (int mt = 0; mt < 4; ++mt) {
    float ria[4];
#pragma unroll
    for (int reg = 0; reg < 4; ++reg)
      ria[reg] = inv_lam / nA[g * NM + m0 + mt * 16 + gq * 4 + reg];
#pragma unroll
    for (int nt = 0; nt < 2; ++nt) {
      const int col = n0 + wv * 32 + nt * 16 + r;
#pragma unroll
      for (int reg = 0; reg < 4; ++reg) {
        const int rw = m0 + mt * 16 + gq * 4 + reg;
        P[(size_t)g * NM * NM + (size_t)rw * 256 + col] =
            expf(acc[mt][nt][reg] * ria[reg] * rnb[nt]);
      }
    }
  }
}

// ---------------- per-row sum of squares (fp32 h) ----------------
__global__ __launch_bounds__(256) void rowsq_k(const float* __restrict__ h,
                                               float* __restrict__ sq) {
  const int w = threadIdx.x >> 6, lane = threadIdx.x & 63;
  const int row = blockIdx.x * 4 + w;
  float4 v = *(const float4*)&h[(size_t)row * ND + lane * 4];
  float s = v.x * v.x + v.y * v.y + v.z * v.z + v.w * v.w;
#pragma unroll
  for (int off = 32; off; off >>= 1) s += __shfl_xor(s, off);
  if (lane == 0) sq[row] = s;
}

// ---------------- per-row L2 norm of bf16 feat ----------------
__global__ __launch_bounds__(256) void normrow_bf_k(const short* __restrict__ feat,
                                                    float* __restrict__ nrm) {
  const int w = threadIdx.x >> 6, lane = threadIdx.x & 63;
  const int row = blockIdx.x * 4 + w;
  const short4 v = *(const short4*)&feat[(size_t)row * ND + lane * 4];
  const float a = bf2f(v.x), b = bf2f(v.y), c = bf2f(v.z), d = bf2f(v.w);
  float s = a * a + b * b + c * c + d * d;
#pragma unroll
  for (int off = 32; off; off >>= 1) s += __shfl_xor(s, off);
  if (lane == 0) nrm[row] = sqrtf(s);
}

// ---------------- top-16 nearest neighbors (wave per row) ----------------
__global__ __launch_bounds__(256) void topk_k(const float* __restrict__ S,
                                              const float* __restrict__ sq,
                                              int* __restrict__ idx) {
  const int w = threadIdx.x >> 6, lane = threadIdx.x & 63;
  const int row = blockIdx.x * 4 + w;
  const int g = row >> 8, m = row & 255;
  const float* Srow = S + (size_t)row * NM;
  const float* sqg = sq + g * NM;
  const float sm = sqg[m];
  const float4 sv = *(const float4*)&Srow[lane * 4];
  const float4 qv = *(const float4*)&sqg[lane * 4];
  float cand[4] = {sm + qv.x - 2.f * sv.x, sm + qv.y - 2.f * sv.y, sm + qv.z - 2.f * sv.z,
                   sm + qv.w - 2.f * sv.w};
#pragma unroll
  for (int t = 0; t < 4; ++t)
    if (lane * 4 + t == m) cand[t] = 1e30f;
  for (int rnd = 0; rnd < NK; ++rnd) {
    float bvv = cand[0];
    int bi = lane * 4;
#pragma unroll
    for (int t = 1; t < 4; ++t)
      if (cand[t] < bvv) {
        bvv = cand[t];
        bi = lane * 4 + t;
      }
#pragma unroll
    for (int off = 1; off < 64; off <<= 1) {
      const float ov = __shfl_xor(bvv, off);
      const int oi = __shfl_xor(bi, off);
      if (ov < bvv || (ov == bvv && oi < bi)) {
        bvv = ov;
        bi = oi;
      }
    }
    if (lane == 0) idx[(size_t)row * NK + rnd] = bi;
    if ((bi >> 2) == lane) cand[bi & 3] = 1e30f;
  }
}

// ---------------- edge MLP via MFMA, 8 waves, bf16 in/out ----------------
__global__ __launch_bounds__(512, 4) void edgemlp_mfma3_k(
    const short* __restrict__ baseb, const short* __restrict__ n1b, const int* __restrict__ idx,
    const short* __restrict__ w2t, const float* __restrict__ b2, short* __restrict__ featbf) {
  __shared__ short E[2][16 * 256];  // 16 KB, XOR-swizzled rows
  __shared__ int sidx[NB * NK];     // 512 ints
  const int tid = threadIdx.x;
  const int l = tid & 63, wv = tid >> 6;
  const int node0 = blockIdx.x * NB;
  const int g = node0 >> 8;
  const int r = l & 15, gq = l >> 4;
  sidx[tid] = idx[(size_t)node0 * NK + tid];
  bf16x8 bfr[2][8];
  float b2v[2];
#pragma unroll
  for (int t = 0; t < 2; ++t) {
    const int nb = wv * 2 + t;
    const short* wb = w2t + (size_t)(nb * 16 + r) * 256 + gq * 8;
#pragma unroll
    for (int ks = 0; ks < 8; ++ks) bfr[t][ks] = *(const bf16x8*)(wb + ks * 32);
    b2v[t] = b2[nb * 16 + r];
  }
  __syncthreads();  // sidx visible
  const int srow = tid >> 5, sc = (tid & 31) * 8;
  const int wbyte = ((srow * 512 + sc * 2) ^ ((srow & 7) << 4));
  bf16x8 bs, ns;
  auto sload = [&](int i) {
    bs = *(const bf16x8*)(baseb + (((size_t)(node0 + i)) << 8) + sc);
    ns = *(const bf16x8*)(n1b + ((((size_t)g << 8) + sidx[i * NK + srow]) << 8) + sc);
  };
  sload(0);
  for (int i = 0; i < NB; ++i) {
    const int buf = i & 1;
    bf16x8 w0;
#pragma unroll
    for (int j = 0; j < 8; ++j) w0[j] = f2bf(fmaxf(bf2f(bs[j]) + bf2f(ns[j]), 0.f));
    *(bf16x8*)((char*)&E[buf][0] + wbyte) = w0;
    __syncthreads();
    if (i + 1 < NB) sload(i + 1);
    f32x4 acc[2];
    acc[0] = (f32x4){0.f, 0.f, 0.f, 0.f};
    acc[1] = (f32x4){0.f, 0.f, 0.f, 0.f};
    const char* eb = (const char*)&E[buf][0];
    const int abase = r * 512 + gq * 16;
#pragma unroll
    for (int ks = 0; ks < 8; ++ks) {
      const bf16x8 a = *(const bf16x8*)(eb + ((abase + ks * 64) ^ ((r & 7) << 4)));
      acc[0] = __builtin_amdgcn_mfma_f32_16x16x32_bf16(a, bfr[0][ks], acc[0], 0, 0, 0);
      acc[1] = __builtin_amdgcn_mfma_f32_16x16x32_bf16(a, bfr[1][ks], acc[1], 0, 0, 0);
    }
#pragma unroll
    for (int t = 0; t < 2; ++t) {
      float m1 = fmaxf(fmaxf(acc[t][0], acc[t][1]), fmaxf(acc[t][2], acc[t][3]));
      m1 = fmaxf(m1, __shfl_xor(m1, 16));
      m1 = fmaxf(m1, __shfl_xor(m1, 32));
      if (gq == 0)
        featbf[(((size_t)(node0 + i)) << 8) + (wv * 2 + t) * 16 + r] = f2bf(m1 + b2v[t]);
    }
  }
}

// ---------------- fused Sinkhorn, plain domain: block per graph, P in regs ----
// P0 = exp(-cost/lam) given; alternately scale rows/cols to sum MASSF.
__global__ __launch_bounds__(1024) void sinkhorn_k(float* __restrict__ P) {
  __shared__ float red[16][256];
  __shared__ float scal[256];
  const int t = threadIdx.x;
  const int tc = t & 15;   // cols tc*16 .. +15
  const int trw = t >> 4;  // rows trw*4 .. +3
  const int wv = t >> 6, l = t & 63;
  float* Pg = P + (size_t)blockIdx.x * NM * NM;
  float p[4][16];
#pragma unroll
  for (int i = 0; i < 4; ++i)
#pragma unroll
    for (int q = 0; q < 4; ++q)
      *(f32x4*)&p[i][q * 4] = *(const f32x4*)&Pg[(size_t)(trw * 4 + i) * NM + tc * 16 + q * 4];

  auto rowpass = [&]() {
#pragma unroll
    for (int i = 0; i < 4; ++i) {
      float s = p[i][0];
#pragma unroll
      for (int j = 1; j < 16; ++j) s += p[i][j];
      s += __shfl_xor(s, 1);
      s += __shfl_xor(s, 2);
      s += __shfl_xor(s, 4);
      s += __shfl_xor(s, 8);
      const float sc = MASSF / s;
#pragma unroll
      for (int j = 0; j < 16; ++j) p[i][j] *= sc;
    }
  };
  auto colpass = [&]() {
    float tmp[16];
#pragma unroll
    for (int j = 0; j < 16; ++j) tmp[j] = ((p[0][j] + p[1][j]) + (p[2][j] + p[3][j]));
#pragma unroll
    for (int j = 0; j < 16; ++j) {
      tmp[j] += __shfl_xor(tmp[j], 16);
      tmp[j] += __shfl_xor(tmp[j], 32);
    }
    if (l < 16) {
#pragma unroll
      for (int q = 0; q < 4; ++q)
        *(f32x4*)&red[wv][l * 16 + q * 4] = *(const f32x4*)&tmp[q * 4];
    }
    __syncthreads();
    if (t < 256) {
      float s = red[0][t];
#pragma unroll
      for (int w = 1; w < 16; ++w) s += red[w][t];
      scal[t] = MASSF / s;
    }
    __syncthreads();
#pragma unroll
    for (int j = 0; j < 16; ++j) {
      const float sc = scal[tc * 16 + j];
#pragma unroll
      for (int i = 0; i < 4; ++i) p[i][j] *= sc;
    }
    __syncthreads();
  };
  for (int it = 0; it < 7; ++it) {
    rowpass();
    colpass();
  }
  rowpass();
#pragma unroll
  for (int i = 0; i < 4; ++i)
#pragma unroll
    for (int q = 0; q < 4; ++q)
      *(f32x4*)&Pg[(size_t)(trw * 4 + i) * NM + tc * 16 + q * 4] = *(const f32x4*)&p[i][q * 4];
}

extern "C" void kernel_launch(void* const* d_in, const int* in_sizes, int n_in, void* d_out,
                              int out_size, void* d_ws, size_t ws_size, hipStream_t stream) {
  const float* tra_x = (const float*)d_in[0];
  const float* det_x = (const float*)d_in[1];
  const float* W_enc = (const float*)d_in[2];
  const float* b_enc = (const float*)d_in[3];
  const float* W1 = (const float*)d_in[4];
  const float* b1 = (const float*)d_in[5];
  const float* W2 = (const float*)d_in[6];
  const float* b2 = (const float*)d_in[7];
  const float* eps = (const float*)d_in[8];
  float* out = (float*)d_out;

  const size_t SZ = (size_t)NR * ND;
  float* h = (float*)d_ws;
  short* hbf = (short*)(h + SZ);
  short* baseb = hbf + SZ;
  short* n1b = baseb + SZ;
  short* featT = n1b + SZ;
  short* featD = featT + SZ;
  float* sq = (float*)(featD + SZ);
  float* nT = sq + NR;
  float* nD = nT + NR;
  int* idx = (int*)(nD + NR);
  short* w2t = (short*)(idx + (size_t)NR * NK);
  short* w1cat = w2t + 256 * 256;
  float* biascat = (float*)(w1cat + 512 * 256);
  float* S = out;  // gram scratch lives in d_out until cost overwrites it

  const float* xs[2] = {tra_x, det_x};
  short* feats[2] = {featT, featD};
  float* nrms[2] = {nT, nD};

  prep_k<<<768, 256, 0, stream>>>(W1, b1, W2, w2t, w1cat, biascat);
  for (int s2 = 0; s2 < 2; ++s2) {
    gemm_nn_k<true, true, true>
        <<<dim3(4, 256), 256, 0, stream>>>(xs[s2], W_enc, b_enc, h, hbf, 256, 256);
    mlp1_mfma_k<<<dim3(4, 256), 256, 0, stream>>>(hbf, w1cat, biascat, baseb, n1b);
    rowsq_k<<<4096, 256, 0, stream>>>(h, sq);
    gemm_nt_k<<<dim3(4, 4, NG), 256, 0, stream>>>(h, h, S);
    topk_k<<<4096, 256, 0, stream>>>(S, sq, idx);
    edgemlp_mfma3_k<<<NR / NB, 512, 0, stream>>>(baseb, n1b, idx, w2t, b2, feats[s2]);
    normrow_bf_k<<<4096, 256, 0, stream>>>(feats[s2], nrms[s2]);
  }
  cost_mfma_k<<<dim3(2, 4, NG), 256, 0, stream>>>(featT, featD, nT, nD, eps, out);
  sinkhorn_k<<<NG, 1024, 0, stream>>>(out);
}

// Round 6
// 398.691 us; speedup vs baseline: 4.9193x; 1.0065x over previous
//
#include <hip/hip_runtime.h>
#include <math.h>

#define NG 64
#define NM 256
#define ND 256
#define NK 16
#define NR (NG * NM)  // 16384 rows total
#define NB 32         // nodes per edge-MLP block

#define MASSF 0.9f

typedef __attribute__((ext_vector_type(8))) short bf16x8;
typedef __attribute__((ext_vector_type(4))) float f32x4;

static __device__ __forceinline__ short f2bf(float x) {
  union {
    float f;
    unsigned u;
  } v;
  v.f = x;
  unsigned r = v.u + 0x7FFFu + ((v.u >> 16) & 1u);
  return (short)(r >> 16);
}
static __device__ __forceinline__ float bf2f(short x) {
  union {
    unsigned u;
    float f;
  } v;
  v.u = ((unsigned)(unsigned short)x) << 16;
  return v.f;
}

// ---------------- prep: W2^T, W1cat = [W1hi - W1lo ; W1lo]^T, biascat ----------
__global__ __launch_bounds__(256) void prep_k(const float* __restrict__ W1,
                                              const float* __restrict__ b1,
                                              const float* __restrict__ W2,
                                              short* __restrict__ w2t, short* __restrict__ w1cat,
                                              float* __restrict__ biascat) {
  const int b = blockIdx.x, k = threadIdx.x;
  if (b < 256) {
    w2t[b * 256 + k] = f2bf(W2[(size_t)k * 256 + b]);
  } else {
    const int n = b - 256;  // 0..511
    float v;
    if (n < 256)
      v = W1[(size_t)k * 256 + n] - W1[(size_t)(k + 256) * 256 + n];
    else
      v = W1[(size_t)(k + 256) * 256 + (n - 256)];
    w1cat[(size_t)n * 256 + k] = f2bf(v);
    if (k == 0) biascat[n] = (n < 256) ? b1[n] : 0.f;
  }
}

// ---------------- encoder GEMM fp32: C = relu(A@B + bias), + bf16 copy --------
// 64x128 tile, 4x8 split micro-tile, dbuf LDS, 1 barrier/K-step.
__global__ __launch_bounds__(256) void gemm_nn2_k(const float* __restrict__ A,
                                                  const float* __restrict__ B,
                                                  const float* __restrict__ bias,
                                                  float* __restrict__ C,
                                                  short* __restrict__ Cbf) {
  __shared__ float As[2][16][68];
  __shared__ float Bs[2][16][128];
  const int tid = threadIdx.x;
  const int tx = tid & 15, ty = tid >> 4;
  const int m0 = blockIdx.y * 64, n0 = blockIdx.x * 128;
  const int arow = tid >> 2, akc = (tid & 3) * 4;
  const int bkr = tid >> 4, bcc = (tid & 15) * 4;
  float4 av, bv0, bv1;
  float acc[4][8] = {};
  auto gload = [&](int k0) {
    av = *(const float4*)&A[(size_t)(m0 + arow) * 256 + k0 + akc];
    bv0 = *(const float4*)&B[(size_t)(k0 + bkr) * 256 + n0 + bcc];
    bv1 = *(const float4*)&B[(size_t)(k0 + bkr) * 256 + n0 + 64 + bcc];
  };
  auto swrite = [&](int buf) {
    As[buf][akc + 0][arow] = av.x;
    As[buf][akc + 1][arow] = av.y;
    As[buf][akc + 2][arow] = av.z;
    As[buf][akc + 3][arow] = av.w;
    *(float4*)&Bs[buf][bkr][bcc] = bv0;
    *(float4*)&Bs[buf][bkr][64 + bcc] = bv1;
  };
  gload(0);
  swrite(0);
  __syncthreads();
  for (int s = 0; s < 16; ++s) {
    if (s < 15) gload((s + 1) * 16);
    const int buf = s & 1;
#pragma unroll
    for (int kk = 0; kk < 16; ++kk) {
      const float4 a0 = *(const float4*)&As[buf][kk][ty * 4];
      const float4 b0 = *(const float4*)&Bs[buf][kk][tx * 4];
      const float4 b1 = *(const float4*)&Bs[buf][kk][64 + tx * 4];
      const float aa[4] = {a0.x, a0.y, a0.z, a0.w};
      const float bb[8] = {b0.x, b0.y, b0.z, b0.w, b1.x, b1.y, b1.z, b1.w};
#pragma unroll
      for (int i = 0; i < 4; ++i)
#pragma unroll
        for (int j = 0; j < 8; ++j) acc[i][j] = fmaf(aa[i], bb[j], acc[i][j]);
    }
    if (s < 15) swrite((s + 1) & 1);
    __syncthreads();
  }
  const float4 bia0 = *(const float4*)&bias[n0 + tx * 4];
  const float4 bia1 = *(const float4*)&bias[n0 + 64 + tx * 4];
#pragma unroll
  for (int i = 0; i < 4; ++i) {
    const size_t row = (size_t)(m0 + ty * 4 + i);
    float4 o0 = {fmaxf(acc[i][0] + bia0.x, 0.f), fmaxf(acc[i][1] + bia0.y, 0.f),
                 fmaxf(acc[i][2] + bia0.z, 0.f), fmaxf(acc[i][3] + bia0.w, 0.f)};
    float4 o1 = {fmaxf(acc[i][4] + bia1.x, 0.f), fmaxf(acc[i][5] + bia1.y, 0.f),
                 fmaxf(acc[i][6] + bia1.z, 0.f), fmaxf(acc[i][7] + bia1.w, 0.f)};
    *(float4*)&C[row * 256 + n0 + tx * 4] = o0;
    *(float4*)&C[row * 256 + n0 + 64 + tx * 4] = o1;
    short4 h0 = {f2bf(o0.x), f2bf(o0.y), f2bf(o0.z), f2bf(o0.w)};
    short4 h1 = {f2bf(o1.x), f2bf(o1.y), f2bf(o1.z), f2bf(o1.w)};
    *(short4*)&Cbf[row * 256 + n0 + tx * 4] = h0;
    *(short4*)&Cbf[row * 256 + n0 + 64 + tx * 4] = h1;
  }
}

// ---------------- symmetric gram NT fp32 per graph: S_g = h_g @ h_g^T --------
// 64x128 tiles; skip lower-left tiles, x=1 tiles mirror-write the transpose.
__global__ __launch_bounds__(256) void gemm_nt2_k(const float* __restrict__ h,
                                                  float* __restrict__ C) {
  const int bx = blockIdx.x, by = blockIdx.y, g = blockIdx.z;
  if (bx == 0 && by >= 2) return;  // covered by mirror of (bx=1, by<2)
  __shared__ float As[2][16][68];
  __shared__ float Bs[2][16][128];
  const float* Ag = h + (size_t)g * NM * ND;
  float* Cg = C + (size_t)g * NM * NM;
  const int tid = threadIdx.x;
  const int tx = tid & 15, ty = tid >> 4;
  const int m0 = by * 64, n0 = bx * 128;
  const int arow = tid >> 2, akc = (tid & 3) * 4;
  const int brow = tid >> 1, bkc = (tid & 1) * 8;
  float4 av, bva, bvb;
  float acc[4][8] = {};
  auto gload = [&](int k0) {
    av = *(const float4*)&Ag[(size_t)(m0 + arow) * 256 + k0 + akc];
    bva = *(const float4*)&Ag[(size_t)(n0 + brow) * 256 + k0 + bkc];
    bvb = *(const float4*)&Ag[(size_t)(n0 + brow) * 256 + k0 + bkc + 4];
  };
  auto swrite = [&](int buf) {
    As[buf][akc + 0][arow] = av.x;
    As[buf][akc + 1][arow] = av.y;
    As[buf][akc + 2][arow] = av.z;
    As[buf][akc + 3][arow] = av.w;
    Bs[buf][bkc + 0][brow] = bva.x;
    Bs[buf][bkc + 1][brow] = bva.y;
    Bs[buf][bkc + 2][brow] = bva.z;
    Bs[buf][bkc + 3][brow] = bva.w;
    Bs[buf][bkc + 4][brow] = bvb.x;
    Bs[buf][bkc + 5][brow] = bvb.y;
    Bs[buf][bkc + 6][brow] = bvb.z;
    Bs[buf][bkc + 7][brow] = bvb.w;
  };
  gload(0);
  swrite(0);
  __syncthreads();
  for (int s = 0; s < 16; ++s) {
    if (s < 15) gload((s + 1) * 16);
    const int buf = s & 1;
#pragma unroll
    for (int kk = 0; kk < 16; ++kk) {
      const float4 a0 = *(const float4*)&As[buf][kk][ty * 4];
      const float4 b0 = *(const float4*)&Bs[buf][kk][tx * 4];
      const float4 b1 = *(const float4*)&Bs[buf][kk][64 + tx * 4];
      const float aa[4] = {a0.x, a0.y, a0.z, a0.w};
      const float bb[8] = {b0.x, b0.y, b0.z, b0.w, b1.x, b1.y, b1.z, b1.w};
#pragma unroll
      for (int i = 0; i < 4; ++i)
#pragma unroll
        for (int j = 0; j < 8; ++j) acc[i][j] = fmaf(aa[i], bb[j], acc[i][j]);
    }
    if (s < 15) swrite((s + 1) & 1);
    __syncthreads();
  }
#pragma unroll
  for (int i = 0; i < 4; ++i) {
    const size_t row = (size_t)(m0 + ty * 4 + i);
    float4 o0 = {acc[i][0], acc[i][1], acc[i][2], acc[i][3]};
    float4 o1 = {acc[i][4], acc[i][5], acc[i][6], acc[i][7]};
    *(float4*)&Cg[row * 256 + n0 + tx * 4] = o0;
    *(float4*)&Cg[row * 256 + n0 + 64 + tx * 4] = o1;
  }
  if (bx == 1 && by < 2) {  // mirror into the skipped lower-left region
#pragma unroll
    for (int j = 0; j < 4; ++j) {
      const size_t col0 = (size_t)(n0 + tx * 4 + j);
      const size_t col1 = (size_t)(n0 + 64 + tx * 4 + j);
      float4 t0 = {acc[0][j], acc[1][j], acc[2][j], acc[3][j]};
      float4 t1 = {acc[0][4 + j], acc[1][4 + j], acc[2][4 + j], acc[3][4 + j]};
      *(float4*)&Cg[col0 * 256 + m0 + ty * 4] = t0;
      *(float4*)&Cg[col1 * 256 + m0 + ty * 4] = t1;
    }
  }
}

// ---------------- MFMA GEMM: [16384,256]bf16 @ w1cat^T -> baseb, n1b (bf16) ---
__global__ __launch_bounds__(256, 2) void mlp1_mfma_k(const short* __restrict__ A,
                                                      const short* __restrict__ Bt,
                                                      const float* __restrict__ biascat,
                                                      short* __restrict__ baseb,
                                                      short* __restrict__ n1b) {
  __shared__ char As[64 * 512];
  const int tid = threadIdx.x;
  const int l = tid & 63, wv = tid >> 6;
  const int r = l & 15, gq = l >> 4;
  const int m0 = blockIdx.y * 64, n0 = blockIdx.x * 128;
  bf16x8 bfr[2][8];
  float bv[2];
#pragma unroll
  for (int nt = 0; nt < 2; ++nt) {
    const int col = n0 + wv * 32 + nt * 16 + r;
    const short* wb = Bt + (size_t)col * 256 + gq * 8;
#pragma unroll
    for (int ks = 0; ks < 8; ++ks) bfr[nt][ks] = *(const bf16x8*)(wb + ks * 32);
    bv[nt] = biascat[col];
  }
  const int row = tid >> 2, ch = tid & 3;
  const char* ag = (const char*)(A + (size_t)(m0 + row) * 256) + ch * 128;
  char* lb = As + row * 512;
#pragma unroll
  for (int j = 0; j < 8; ++j)
    *(bf16x8*)(lb + (((ch * 128 + j * 16)) ^ ((row & 7) << 4))) = *(const bf16x8*)(ag + j * 16);
  __syncthreads();
  f32x4 acc[4][2];
#pragma unroll
  for (int mt = 0; mt < 4; ++mt)
#pragma unroll
    for (int nt = 0; nt < 2; ++nt) acc[mt][nt] = (f32x4){0.f, 0.f, 0.f, 0.f};
#pragma unroll
  for (int ks = 0; ks < 8; ++ks) {
    bf16x8 a[4];
#pragma unroll
    for (int mt = 0; mt < 4; ++mt)
      a[mt] = *(const bf16x8*)(As + (mt * 16 + r) * 512 + ((gq * 16 + ks * 64) ^ ((r & 7) << 4)));
#pragma unroll
    for (int mt = 0; mt < 4; ++mt)
#pragma unroll
      for (int nt = 0; nt < 2; ++nt)
        acc[mt][nt] = __builtin_amdgcn_mfma_f32_16x16x32_bf16(a[mt], bfr[nt][ks], acc[mt][nt], 0, 0, 0);
  }
  short* dst = (n0 < 256) ? baseb : n1b;
  const int cb = (n0 < 256) ? n0 : n0 - 256;
#pragma unroll
  for (int mt = 0; mt < 4; ++mt)
#pragma unroll
    for (int nt = 0; nt < 2; ++nt) {
      const int col = cb + wv * 32 + nt * 16 + r;
#pragma unroll
      for (int reg = 0; reg < 4; ++reg) {
        const int rw = m0 + mt * 16 + gq * 4 + reg;
        dst[(size_t)rw * 256 + col] = f2bf(acc[mt][nt][reg] + bv[nt]);
      }
    }
}

// ---------------- MFMA cost GEMM -> P0 = exp(corr/(nA nB lam)), batched --------
__global__ __launch_bounds__(256, 2) void cost_mfma_k(const short* __restrict__ featT,
                                                      const short* __restrict__ featD,
                                                      const float* __restrict__ nA,
                                                      const float* __restrict__ nB,
                                                      const float* __restrict__ eps,
                                                      float* __restrict__ P) {
  __shared__ char As[64 * 512];
  const int g = blockIdx.z;
  const short* A = featT + (size_t)g * NM * ND;
  const short* Bt = featD + (size_t)g * NM * ND;
  const int tid = threadIdx.x;
  const int l = tid & 63, wv = tid >> 6;
  const int r = l & 15, gq = l >> 4;
  const int m0 = blockIdx.y * 64, n0 = blockIdx.x * 128;
  bf16x8 bfr[2][8];
  float rnb[2];
#pragma unroll
  for (int nt = 0; nt < 2; ++nt) {
    const int col = n0 + wv * 32 + nt * 16 + r;
    const short* wb = Bt + (size_t)col * 256 + gq * 8;
#pragma unroll
    for (int ks = 0; ks < 8; ++ks) bfr[nt][ks] = *(const bf16x8*)(wb + ks * 32);
    rnb[nt] = 1.0f / nB[g * NM + col];
  }
  const int row = tid >> 2, ch = tid & 3;
  const char* ag = (const char*)(A + (size_t)(m0 + row) * 256) + ch * 128;
  char* lb = As + row * 512;
#pragma unroll
  for (int j = 0; j < 8; ++j)
    *(bf16x8*)(lb + (((ch * 128 + j * 16)) ^ ((row & 7) << 4))) = *(const bf16x8*)(ag + j * 16);
  __syncthreads();
  f32x4 acc[4][2];
#pragma unroll
  for (int mt = 0; mt < 4; ++mt)
#pragma unroll
    for (int nt = 0; nt < 2; ++nt) acc[mt][nt] = (f32x4){0.f, 0.f, 0.f, 0.f};
#pragma unroll
  for (int ks = 0; ks < 8; ++ks) {
    bf16x8 a[4];
#pragma unroll
    for (int mt = 0; mt < 4; ++mt)
      a[mt] = *(const bf16x8*)(As + (mt * 16 + r) * 512 + ((gq * 16 + ks * 64) ^ ((r & 7) << 4)));
#pragma unroll
    for (int mt = 0; mt < 4; ++mt)
#pragma unroll
      for (int nt = 0; nt < 2; ++nt)
        acc[mt][nt] = __builtin_amdgcn_mfma_f32_16x16x32_bf16(a[mt], bfr[nt][ks], acc[mt][nt], 0, 0, 0);
  }
  const float inv_lam = 1.0f / (expf(eps[0]) + 0.03f);
#pragma unroll
  for (int mt = 0; mt < 4; ++mt) {
    float ria[4];
#pragma unroll
    for (int reg = 0; reg < 4; ++reg)
      ria[reg] = inv_lam / nA[g * NM + m0 + mt * 16 + gq * 4 + reg];
#pragma unroll
    for (int nt = 0; nt < 2; ++nt) {
      const int col = n0 + wv * 32 + nt * 16 + r;
#pragma unroll
      for (int reg = 0; reg < 4; ++reg) {
        const int rw = m0 + mt * 16 + gq * 4 + reg;
        P[(size_t)g * NM * NM + (size_t)rw * 256 + col] =
            expf(acc[mt][nt][reg] * ria[reg] * rnb[nt]);
      }
    }
  }
}

// ---------------- per-row sum of squares (fp32 h) ----------------
__global__ __launch_bounds__(256) void rowsq_k(const float* __restrict__ h,
                                               float* __restrict__ sq) {
  const int w = threadIdx.x >> 6, lane = threadIdx.x & 63;
  const int row = blockIdx.x * 4 + w;
  float4 v = *(const float4*)&h[(size_t)row * ND + lane * 4];
  float s = v.x * v.x + v.y * v.y + v.z * v.z + v.w * v.w;
#pragma unroll
  for (int off = 32; off; off >>= 1) s += __shfl_xor(s, off);
  if (lane == 0) sq[row] = s;
}

// ---------------- per-row L2 norm of bf16 feat ----------------
__global__ __launch_bounds__(256) void normrow_bf_k(const short* __restrict__ feat,
                                                    float* __restrict__ nrm) {
  const int w = threadIdx.x >> 6, lane = threadIdx.x & 63;
  const int row = blockIdx.x * 4 + w;
  const short4 v = *(const short4*)&feat[(size_t)row * ND + lane * 4];
  const float a = bf2f(v.x), b = bf2f(v.y), c = bf2f(v.z), d = bf2f(v.w);
  float s = a * a + b * b + c * c + d * d;
#pragma unroll
  for (int off = 32; off; off >>= 1) s += __shfl_xor(s, off);
  if (lane == 0) nrm[row] = sqrtf(s);
}

// ---------------- top-16 nearest neighbors (wave per row) ----------------
__global__ __launch_bounds__(256) void topk_k(const float* __restrict__ S,
                                              const float* __restrict__ sq,
                                              int* __restrict__ idx) {
  const int w = threadIdx.x >> 6, lane = threadIdx.x & 63;
  const int row = blockIdx.x * 4 + w;
  const int g = row >> 8, m = row & 255;
  const float* Srow = S + (size_t)row * NM;
  const float* sqg = sq + g * NM;
  const float sm = sqg[m];
  const float4 sv = *(const float4*)&Srow[lane * 4];
  const float4 qv = *(const float4*)&sqg[lane * 4];
  float cand[4] = {sm + qv.x - 2.f * sv.x, sm + qv.y - 2.f * sv.y, sm + qv.z - 2.f * sv.z,
                   sm + qv.w - 2.f * sv.w};
#pragma unroll
  for (int t = 0; t < 4; ++t)
    if (lane * 4 + t == m) cand[t] = 1e30f;
  for (int rnd = 0; rnd < NK; ++rnd) {
    float bvv = cand[0];
    int bi = lane * 4;
#pragma unroll
    for (int t = 1; t < 4; ++t)
      if (cand[t] < bvv) {
        bvv = cand[t];
        bi = lane * 4 + t;
      }
#pragma unroll
    for (int off = 1; off < 64; off <<= 1) {
      const float ov = __shfl_xor(bvv, off);
      const int oi = __shfl_xor(bi, off);
      if (ov < bvv || (ov == bvv && oi < bi)) {
        bvv = ov;
        bi = oi;
      }
    }
    if (lane == 0) idx[(size_t)row * NK + rnd] = bi;
    if ((bi >> 2) == lane) cand[bi & 3] = 1e30f;
  }
}

// ---------------- edge MLP via MFMA v4: 2-node stages, dbuf, 1 barrier/stage --
__global__ __launch_bounds__(512, 4) void edgemlp_mfma4_k(
    const short* __restrict__ baseb, const short* __restrict__ n1b, const int* __restrict__ idx,
    const short* __restrict__ w2t, const float* __restrict__ b2, short* __restrict__ featbf) {
  __shared__ short E[2][32 * 256];  // 2 x 16 KB, XOR-swizzled rows
  __shared__ int sidx[NB * NK];     // 512 ints
  const int tid = threadIdx.x;
  const int l = tid & 63, wv = tid >> 6;
  const int node0 = blockIdx.x * NB;
  const int g = node0 >> 8;
  const int r = l & 15, gq = l >> 4;
  sidx[tid] = idx[(size_t)node0 * NK + tid];
  bf16x8 bfr[2][8];
  float b2v[2];
#pragma unroll
  for (int t = 0; t < 2; ++t) {
    const int nb = wv * 2 + t;
    const short* wb = w2t + (size_t)(nb * 16 + r) * 256 + gq * 8;
#pragma unroll
    for (int ks = 0; ks < 8; ++ks) bfr[t][ks] = *(const bf16x8*)(wb + ks * 32);
    b2v[t] = b2[nb * 16 + r];
  }
  __syncthreads();  // sidx visible
  const int j = tid >> 5;        // row within node 0..15
  const int c = (tid & 31) * 8;  // col
  const unsigned wboff = (unsigned)((c * 2) ^ ((j & 7) << 4));
  bf16x8 ns0, ns1;
  auto sload = [&](int s) {  // issue n1 gathers for stage s (2 nodes)
    const int nb0 = s * 2;
    ns0 = *(const bf16x8*)(n1b + ((((size_t)g << 8) + sidx[nb0 * NK + j]) << 8) + c);
    ns1 = *(const bf16x8*)(n1b + ((((size_t)g << 8) + sidx[(nb0 + 1) * NK + j]) << 8) + c);
  };
  auto swrite = [&](int s) {  // relu(base+n1) -> bf16 swizzled LDS
    char* eb = (char*)&E[s & 1][0];
    const int nb0 = s * 2;
    const bf16x8 b0 = *(const bf16x8*)(baseb + (((size_t)(node0 + nb0)) << 8) + c);
    const bf16x8 b1 = *(const bf16x8*)(baseb + (((size_t)(node0 + nb0 + 1)) << 8) + c);
    bf16x8 w0, w1;
#pragma unroll
    for (int q = 0; q < 8; ++q) {
      w0[q] = f2bf(fmaxf(bf2f(b0[q]) + bf2f(ns0[q]), 0.f));
      w1[q] = f2bf(fmaxf(bf2f(b1[q]) + bf2f(ns1[q]), 0.f));
    }
    *(bf16x8*)(eb + (size_t)j * 512 + wboff) = w0;
    *(bf16x8*)(eb + (size_t)(16 + j) * 512 + wboff) = w1;
  };
  sload(0);
  swrite(0);
  __syncthreads();
  for (int s = 0; s < NB / 2; ++s) {
    if (s + 1 < NB / 2) sload(s + 1);
    const char* eb = (const char*)&E[s & 1][0];
#pragma unroll
    for (int q = 0; q < 2; ++q) {
      f32x4 acc0 = (f32x4){0.f, 0.f, 0.f, 0.f};
      f32x4 acc1 = (f32x4){0.f, 0.f, 0.f, 0.f};
      const int rowb = (q * 16 + r) * 512;
#pragma unroll
      for (int ks = 0; ks < 8; ++ks) {
        const bf16x8 a = *(const bf16x8*)(eb + rowb + ((gq * 16 + ks * 64) ^ ((r & 7) << 4)));
        acc0 = __builtin_amdgcn_mfma_f32_16x16x32_bf16(a, bfr[0][ks], acc0, 0, 0, 0);
        acc1 = __builtin_amdgcn_mfma_f32_16x16x32_bf16(a, bfr[1][ks], acc1, 0, 0, 0);
      }
      const int nd = node0 + s * 2 + q;
      float m0v = fmaxf(fmaxf(acc0[0], acc0[1]), fmaxf(acc0[2], acc0[3]));
      m0v = fmaxf(m0v, __shfl_xor(m0v, 16));
      m0v = fmaxf(m0v, __shfl_xor(m0v, 32));
      float m1v = fmaxf(fmaxf(acc1[0], acc1[1]), fmaxf(acc1[2], acc1[3]));
      m1v = fmaxf(m1v, __shfl_xor(m1v, 16));
      m1v = fmaxf(m1v, __shfl_xor(m1v, 32));
      if (gq == 0) {
        featbf[((size_t)nd << 8) + (wv * 2 + 0) * 16 + r] = f2bf(m0v + b2v[0]);
        featbf[((size_t)nd << 8) + (wv * 2 + 1) * 16 + r] = f2bf(m1v + b2v[1]);
      }
    }
    if (s + 1 < NB / 2) swrite(s + 1);
    __syncthreads();
  }
}

// ---------------- fused Sinkhorn, plain domain: block per graph, P in regs ----
__global__ __launch_bounds__(1024) void sinkhorn_k(float* __restrict__ P) {
  __shared__ float red[16][256];
  __shared__ float scal[256];
  const int t = threadIdx.x;
  const int tc = t & 15;
  const int trw = t >> 4;
  const int wv = t >> 6, l = t & 63;
  float* Pg = P + (size_t)blockIdx.x * NM * NM;
  float p[4][16];
#pragma unroll
  for (int i = 0; i < 4; ++i)
#pragma unroll
    for (int q = 0; q < 4; ++q)
      *(f32x4*)&p[i][q * 4] = *(const f32x4*)&Pg[(size_t)(trw * 4 + i) * NM + tc * 16 + q * 4];

  auto rowpass = [&]() {
#pragma unroll
    for (int i = 0; i < 4; ++i) {
      float s = p[i][0];
#pragma unroll
      for (int j = 1; j < 16; ++j) s += p[i][j];
      s += __shfl_xor(s, 1);
      s += __shfl_xor(s, 2);
      s += __shfl_xor(s, 4);
      s += __shfl_xor(s, 8);
      const float sc = MASSF / s;
#pragma unroll
      for (int j = 0; j < 16; ++j) p[i][j] *= sc;
    }
  };
  auto colpass = [&]() {
    float tmp[16];
#pragma unroll
    for (int j = 0; j < 16; ++j) tmp[j] = ((p[0][j] + p[1][j]) + (p[2][j] + p[3][j]));
#pragma unroll
    for (int j = 0; j < 16; ++j) {
      tmp[j] += __shfl_xor(tmp[j], 16);
      tmp[j] += __shfl_xor(tmp[j], 32);
    }
    if (l < 16) {
#pragma unroll
      for (int q = 0; q < 4; ++q)
        *(f32x4*)&red[wv][l * 16 + q * 4] = *(const f32x4*)&tmp[q * 4];
    }
    __syncthreads();
    if (t < 256) {
      float s = red[0][t];
#pragma unroll
      for (int w = 1; w < 16; ++w) s += red[w][t];
      scal[t] = MASSF / s;
    }
    __syncthreads();
#pragma unroll
    for (int j = 0; j < 16; ++j) {
      const float sc = scal[tc * 16 + j];
#pragma unroll
      for (int i = 0; i < 4; ++i) p[i][j] *= sc;
    }
    __syncthreads();
  };
  for (int it = 0; it < 7; ++it) {
    rowpass();
    colpass();
  }
  rowpass();
#pragma unroll
  for (int i = 0; i < 4; ++i)
#pragma unroll
    for (int q = 0; q < 4; ++q)
      *(f32x4*)&Pg[(size_t)(trw * 4 + i) * NM + tc * 16 + q * 4] = *(const f32x4*)&p[i][q * 4];
}

extern "C" void kernel_launch(void* const* d_in, const int* in_sizes, int n_in, void* d_out,
                              int out_size, void* d_ws, size_t ws_size, hipStream_t stream) {
  const float* tra_x = (const float*)d_in[0];
  const float* det_x = (const float*)d_in[1];
  const float* W_enc = (const float*)d_in[2];
  const float* b_enc = (const float*)d_in[3];
  const float* W1 = (const float*)d_in[4];
  const float* b1 = (const float*)d_in[5];
  const float* W2 = (const float*)d_in[6];
  const float* b2 = (const float*)d_in[7];
  const float* eps = (const float*)d_in[8];
  float* out = (float*)d_out;

  const size_t SZ = (size_t)NR * ND;
  float* h = (float*)d_ws;
  short* hbf = (short*)(h + SZ);
  short* baseb = hbf + SZ;
  short* n1b = baseb + SZ;
  short* featT = n1b + SZ;
  short* featD = featT + SZ;
  float* sq = (float*)(featD + SZ);
  float* nT = sq + NR;
  float* nD = nT + NR;
  int* idx = (int*)(nD + NR);
  short* w2t = (short*)(idx + (size_t)NR * NK);
  short* w1cat = w2t + 256 * 256;
  float* biascat = (float*)(w1cat + 512 * 256);
  float* S = out;  // gram scratch lives in d_out until cost overwrites it

  const float* xs[2] = {tra_x, det_x};
  short* feats[2] = {featT, featD};
  float* nrms[2] = {nT, nD};

  prep_k<<<768, 256, 0, stream>>>(W1, b1, W2, w2t, w1cat, biascat);
  for (int s2 = 0; s2 < 2; ++s2) {
    gemm_nn2_k<<<dim3(2, 256), 256, 0, stream>>>(xs[s2], W_enc, b_enc, h, hbf);
    mlp1_mfma_k<<<dim3(4, 256), 256, 0, stream>>>(hbf, w1cat, biascat, baseb, n1b);
    rowsq_k<<<4096, 256, 0, stream>>>(h, sq);
    gemm_nt2_k<<<dim3(2, 4, NG), 256, 0, stream>>>(h, S);
    topk_k<<<4096, 256, 0, stream>>>(S, sq, idx);
    edgemlp_mfma4_k<<<NR / NB, 512, 0, stream>>>(baseb, n1b, idx, w2t, b2, feats[s2]);
    normrow_bf_k<<<4096, 256, 0, stream>>>(feats[s2], nrms[s2]);
  }
  cost_mfma_k<<<dim3(2, 4, NG), 256, 0, stream>>>(featT, featD, nT, nD, eps, out);
  sinkhorn_k<<<NG, 1024, 0, stream>>>(out);
}